// Round 7
// baseline (654.317 us; speedup 1.0000x reference)
//
#include <hip/hip_runtime.h>
#include <hip/hip_bf16.h>
#include <cstdint>

#define N_NODES 4096
#define F_IN    1433
#define N_EDGE  131072

typedef short short8v __attribute__((ext_vector_type(8)));
typedef float f32x4 __attribute__((ext_vector_type(4)));

#define GLOBAL_AS __attribute__((address_space(1)))
#define LDS_AS    __attribute__((address_space(3)))

__device__ __forceinline__ void gload_lds16(const void* g, void* l) {
  __builtin_amdgcn_global_load_lds((const GLOBAL_AS void*)g, (LDS_AS void*)l, 16, 0, 0);
}

__device__ __forceinline__ float bf16_to_f32(unsigned short u) {
  union { unsigned u; float f; } c;
  c.u = ((unsigned)u) << 16;
  return c.f;
}

__device__ __forceinline__ unsigned short f32_to_bf16_rne(float f) {
  union { float f; unsigned u; } c; c.f = f;
  unsigned u = c.u;
  return (unsigned short)((u + 0x7FFFu + ((u >> 16) & 1u)) >> 16);
}

// exact 3-way bf16 split: a+b+c == v (covers 24 mantissa bits)
__device__ __forceinline__ void split3(float v, unsigned short& a,
                                       unsigned short& b, unsigned short& c) {
  a = f32_to_bf16_rne(v); float r0 = v - bf16_to_f32(a);
  b = f32_to_bf16_rne(r0); float r1 = r0 - bf16_to_f32(b);
  c = f32_to_bf16_rne(r1);
}

// ---------------- adjacency build (bf16 only; exact {0,1}) ----------------

__global__ void scatter_edges_k(const int* __restrict__ e0, const int* __restrict__ e1,
                                unsigned short* __restrict__ Ab, int n, int ne) {
  int t = blockIdx.x * 256 + threadIdx.x;
  if (t >= ne) return;
  int u = e0[t], v = e1[t];
  if (u != v) {
    Ab[(size_t)u * n + v] = 0x3F80;  // bf16 1.0
    Ab[(size_t)v * n + u] = 0x3F80;
  }
}

// deg = rowsum + 2, dinv = 1/sqrt(deg); bf16 input (exact small ints)
__global__ void deg_dinv_bf16_k(const unsigned short* __restrict__ A,
                                float* __restrict__ dinv, int n) {
  int wid  = (blockIdx.x * blockDim.x + threadIdx.x) >> 6;
  int lane = threadIdx.x & 63;
  if (wid >= n) return;
  const unsigned short* row = A + (size_t)wid * n;
  float s = 0.f;
  for (int j = lane * 8; j < n; j += 512) {
    uint4 v = *(const uint4*)(row + j);
    s += bf16_to_f32((unsigned short)(v.x & 0xffff)) + bf16_to_f32((unsigned short)(v.x >> 16));
    s += bf16_to_f32((unsigned short)(v.y & 0xffff)) + bf16_to_f32((unsigned short)(v.y >> 16));
    s += bf16_to_f32((unsigned short)(v.z & 0xffff)) + bf16_to_f32((unsigned short)(v.z >> 16));
    s += bf16_to_f32((unsigned short)(v.w & 0xffff)) + bf16_to_f32((unsigned short)(v.w >> 16));
  }
#pragma unroll
  for (int off = 32; off > 0; off >>= 1) s += __shfl_down(s, off, 64);
  if (lane == 0) {
    float d = s + 2.0f;
    dinv[wid] = d > 0.f ? 1.0f / sqrtf(d) : 0.f;
  }
}

__global__ void deg_dinv_f32_k(const float* __restrict__ A, float* __restrict__ dinv, int n) {
  int wid  = (blockIdx.x * blockDim.x + threadIdx.x) >> 6;
  int lane = threadIdx.x & 63;
  if (wid >= n) return;
  const float* row = A + (size_t)wid * n;
  float s = 0.f;
  for (int j = lane * 4; j < n; j += 256) {
    float4 v = *(const float4*)(row + j);
    s += (v.x + v.y) + (v.z + v.w);
  }
#pragma unroll
  for (int off = 32; off > 0; off >>= 1) s += __shfl_down(s, off, 64);
  if (lane == 0) {
    float d = s + 2.0f;
    dinv[wid] = d > 0.f ? 1.0f / sqrtf(d) : 0.f;
  }
}

// ---------------- row gathers (Ap = M[perm, :]) ----------------

__global__ void gather_rows_bf16_k(const unsigned short* __restrict__ src,
                                   const int* __restrict__ perm,
                                   unsigned short* __restrict__ dst, int K, int cbits) {
  size_t t = (size_t)blockIdx.x * 256 + threadIdx.x;
  int r  = (int)(t >> cbits);
  int c8 = (int)(t & ((1u << cbits) - 1));
  uint4 v = *(const uint4*)(src + (size_t)perm[r] * K + c8 * 8);
  *(uint4*)(dst + t * 8) = v;
}

__global__ void gather_rows_f32_k(const float* __restrict__ src,
                                  const int* __restrict__ perm,
                                  float* __restrict__ dst, int K, int cbits) {
  size_t t = (size_t)blockIdx.x * 256 + threadIdx.x;
  int r  = (int)(t >> cbits);
  int c4 = (int)(t & ((1u << cbits) - 1));
  float4 v = *(const float4*)(src + (size_t)perm[r] * K + c4 * 4);
  *(float4*)(dst + t * 4) = v;
}

// ---------------- pooled augment via bf16 MFMA (8 waves, XCD-chunked) --------
// out[r][s] = dot(Ap[r,:], Ap[s,:]) + 2*Ap[r][perm[s]], diag 0.
// LDS slot-swizzle: slot' = slot ^ ((row>>1)&3) applied to BOTH the global
// source of gload_lds (dest stays linear) and the ds_read slot.

__device__ __forceinline__ void block_map(int bid, int nb, int& bx, int& by) {
  if (nb == 16) {
    int xcd = bid & 7, idx = bid >> 3;
    by = (xcd >> 1) * 4 + (idx >> 3);
    bx = (xcd & 1) * 8 + (idx & 7);
  } else if (nb == 8) {
    int xcd = bid & 7, idx = bid >> 3;
    by = (xcd >> 1) * 2 + (idx >> 2);
    bx = (xcd & 1) * 4 + (idx & 3);
  } else {
    bx = bid % nb; by = bid / nb;
  }
}

__global__ __launch_bounds__(512) void gemm_bf16_pool_k(
    const __hip_bfloat16* __restrict__ Ap, const int* __restrict__ perm,
    float* __restrict__ outF, unsigned short* __restrict__ outB, int M, int K) {
  __shared__ short lds[2][2][128 * 32];
  int nb = M >> 7;
  int bx, by; block_map(blockIdx.x, nb, bx, by);
  int row0 = by << 7, col0 = bx << 7;
  int tid = threadIdx.x;
  int wv = tid >> 6, ln = tid & 63;
  int lr = ln & 15, kh = ln >> 4;
  int wr = wv >> 2, wc = wv & 3;   // 2x4 wave grid; wave tile 64x32

  f32x4 acc[4][2] = {};

  auto stage = [&](int buf, int k0) {
#pragma unroll
    for (int t = 0; t < 2; ++t) {
      int rbase = t ? col0 : row0;
      int row = tid >> 2;
      int gslot = (tid & 3) ^ ((row >> 1) & 3);   // pre-swizzled source slot
      const char* g = (const char*)(Ap + (size_t)(rbase + row) * K + k0) + gslot * 16;
      gload_lds16(g, (char*)&lds[buf][t][0] + wv * 1024);  // wave-uniform base
    }
  };

  int sA = kh ^ ((lr >> 1) & 3);  // read-side swizzled slot (shorts offset sA*8)
  int nt = K >> 5;
  stage(0, 0);
  int cur = 0;
  for (int kt = 0; kt < nt; ++kt) {
    __syncthreads();
    if (kt + 1 < nt) stage(cur ^ 1, (kt + 1) << 5);
    const short* AbL = &lds[cur][0][0];
    const short* BbL = &lds[cur][1][0];
    short8v af[4], bfr[2];
#pragma unroll
    for (int m = 0; m < 4; ++m)
      af[m] = *(const short8v*)(AbL + (wr * 64 + m * 16 + lr) * 32 + sA * 8);
#pragma unroll
    for (int q = 0; q < 2; ++q)
      bfr[q] = *(const short8v*)(BbL + (wc * 32 + q * 16 + lr) * 32 + sA * 8);
#pragma unroll
    for (int m = 0; m < 4; ++m)
#pragma unroll
      for (int q = 0; q < 2; ++q)
        acc[m][q] = __builtin_amdgcn_mfma_f32_16x16x32_bf16(af[m], bfr[q], acc[m][q], 0, 0, 0);
    cur ^= 1;
  }

#pragma unroll
  for (int q = 0; q < 2; ++q) {
    int col = col0 + wc * 32 + q * 16 + lr;
    int pc  = perm[col];
#pragma unroll
    for (int m = 0; m < 4; ++m) {
      int rb = row0 + wr * 64 + m * 16 + kh * 4;
#pragma unroll
      for (int r = 0; r < 4; ++r) {
        int row = rb + r;
        float v = acc[m][q][r] +
                  2.0f * bf16_to_f32(((const unsigned short*)Ap)[(size_t)row * K + pc]);
        if (row == col) v = 0.f;
        if (outF) outF[(size_t)row * M + col] = v;
        if (outB) {
          union { float f; unsigned u; } c2; c2.f = v;
          outB[(size_t)row * M + col] = (unsigned short)(c2.u >> 16);  // exact small int
        }
      }
    }
  }
}

// ---------------- pooled augment f32 (level 3) ----------------

__global__ __launch_bounds__(256) void gemm_f32_pool_k(
    const float* __restrict__ Ap, const int* __restrict__ perm,
    float* __restrict__ outF, int M, int K) {
  __shared__ float As[32][33];
  __shared__ float Bs[32][33];
  int nb = M >> 5;
  int bx = blockIdx.x % nb, by = blockIdx.x / nb;
  int row0 = by << 5, col0 = bx << 5;
  int tid = threadIdx.x;
  int tr = tid >> 4, tc = tid & 15;
  int lr = tid >> 3, lq = (tid & 7) * 4;
  float acc[2][2] = {};
  for (int k0 = 0; k0 < K; k0 += 32) {
    float4 av = *(const float4*)(Ap + (size_t)(row0 + lr) * K + k0 + lq);
    float4 bv = *(const float4*)(Ap + (size_t)(col0 + lr) * K + k0 + lq);
    __syncthreads();
    As[lq + 0][lr] = av.x; As[lq + 1][lr] = av.y;
    As[lq + 2][lr] = av.z; As[lq + 3][lr] = av.w;
    Bs[lq + 0][lr] = bv.x; Bs[lq + 1][lr] = bv.y;
    Bs[lq + 2][lr] = bv.z; Bs[lq + 3][lr] = bv.w;
    __syncthreads();
#pragma unroll
    for (int k = 0; k < 32; ++k) {
      float2 a = *(const float2*)&As[k][tr * 2];
      float2 b = *(const float2*)&Bs[k][tc * 2];
      acc[0][0] += a.x * b.x; acc[0][1] += a.x * b.y;
      acc[1][0] += a.y * b.x; acc[1][1] += a.y * b.y;
    }
  }
#pragma unroll
  for (int j = 0; j < 2; ++j) {
    int col = col0 + tc * 2 + j;
    int pc = perm[col];
#pragma unroll
    for (int i = 0; i < 2; ++i) {
      int row = row0 + tr * 2 + i;
      float v = acc[i][j] + 2.0f * Ap[(size_t)row * K + pc];
      if (row == col) v = 0.f;
      outF[(size_t)row * M + col] = v;
    }
  }
}

// ---------------- Z = dinv_i * (X @ W), 4-acc ILP; optional T emission -------
template <int K2, int EMIT_T>
__global__ void xw_scale_k(const float* __restrict__ X, const float* __restrict__ W,
                           const float* __restrict__ dinv, float* __restrict__ Z,
                           unsigned short* __restrict__ T0, unsigned short* __restrict__ T1,
                           unsigned short* __restrict__ T2, int n, int K1, int relu_in) {
  __shared__ float Xs[8][128];
  int tx = threadIdx.x, ty = threadIdx.y;
  int i0 = blockIdx.x * 8;
  int tid = ty * 32 + tx;
  float acc0 = 0.f, acc1 = 0.f, acc2 = 0.f, acc3 = 0.f;
  for (int k0 = 0; k0 < K1; k0 += 128) {
    __syncthreads();
#pragma unroll
    for (int l = 0; l < 4; ++l) {
      int idx = tid + l * 256;
      int r = idx >> 7, kk = idx & 127;
      float xv = (k0 + kk < K1) ? X[(size_t)(i0 + r) * K1 + k0 + kk] : 0.f;
      if (relu_in) xv = fmaxf(xv, 0.f);
      Xs[r][kk] = xv;
    }
    __syncthreads();
    if (tx < K2) {
      int lim = min(128, K1 - k0);
      int kk = 0;
      for (; kk + 3 < lim; kk += 4) {
        acc0 += Xs[ty][kk + 0] * W[(size_t)(k0 + kk + 0) * K2 + tx];
        acc1 += Xs[ty][kk + 1] * W[(size_t)(k0 + kk + 1) * K2 + tx];
        acc2 += Xs[ty][kk + 2] * W[(size_t)(k0 + kk + 2) * K2 + tx];
        acc3 += Xs[ty][kk + 3] * W[(size_t)(k0 + kk + 3) * K2 + tx];
      }
      for (; kk < lim; ++kk)
        acc0 += Xs[ty][kk] * W[(size_t)(k0 + kk) * K2 + tx];
    }
  }
  if (tx < K2) {
    float z = dinv[i0 + ty] * ((acc0 + acc1) + (acc2 + acc3));
    Z[(size_t)(i0 + ty) * K2 + tx] = z;
    if (EMIT_T) {  // prescaled semantics: split(z)
      unsigned short a, b, c; split3(z, a, b, c);
      size_t o = (size_t)tx * n + i0 + ty;
      T0[o] = a; T1[o] = b; T2[o] = c;
    }
  }
}

// ---------------- MFMA GCN aggregation (bf16-exact A) ------------------------
// C^T[32 feat][16 nodes] per block via 8-wave K-split + fused epilogue.
// Optionally emits the next layer's T-split (To*) from its own output.

template <int HAS_W, int HCO, int LOGSM, int EMIT_T, int EMIT_RELU>
__global__ __launch_bounds__(512) void agg_mfma_k(
    const unsigned short* __restrict__ Aadj,
    const unsigned short* __restrict__ T0, const unsigned short* __restrict__ T1,
    const unsigned short* __restrict__ T2,
    const float* __restrict__ X, const float* __restrict__ dinv,
    const float* __restrict__ W, const float* __restrict__ bias,
    float* __restrict__ out,
    unsigned short* __restrict__ To0, unsigned short* __restrict__ To1,
    unsigned short* __restrict__ To2,
    int n, int prescaled, int relu_in, int relu_out) {
  __shared__ float yw[8][32][17];
  __shared__ float Ws[32][32];
  __shared__ float ytot[32][17];
  __shared__ float Os[16][8];
  __shared__ float bs[32];
  int tid = threadIdx.x;
  int wv = tid >> 6, ln = tid & 63;
  int lr = ln & 15, kh = ln >> 4;
  int node0 = blockIdx.x * 16;

  if (HAS_W) {
    if (HCO == 32) {
#pragma unroll
      for (int l = 0; l < 2; ++l) {
        int idx = tid + l * 512;
        Ws[idx >> 5][idx & 31] = W[idx];
      }
    } else {
      if (tid < 32 * HCO) Ws[tid / HCO][tid % HCO] = W[tid];
    }
  }
  if (tid < HCO) bs[tid] = bias[tid];

  int kper = n >> 3;
  int kbeg = wv * kper;
  const unsigned short* Ar = Aadj + (size_t)(node0 + lr) * n + kh * 8;
  const unsigned short* t0 = T0 + (size_t)lr * n + kh * 8;
  const unsigned short* t1 = T1 + (size_t)lr * n + kh * 8;
  const unsigned short* t2 = T2 + (size_t)lr * n + kh * 8;
  const size_t m16 = (size_t)16 * n;

  f32x4 acc0 = {0.f, 0.f, 0.f, 0.f}, acc1 = {0.f, 0.f, 0.f, 0.f};
  for (int k = kbeg; k < kbeg + kper; k += 32) {
    short8v b   = *(const short8v*)(Ar + k);
    short8v a00 = *(const short8v*)(t0 + k);
    short8v a01 = *(const short8v*)(t0 + m16 + k);
    short8v a10 = *(const short8v*)(t1 + k);
    short8v a11 = *(const short8v*)(t1 + m16 + k);
    short8v a20 = *(const short8v*)(t2 + k);
    short8v a21 = *(const short8v*)(t2 + m16 + k);
    acc0 = __builtin_amdgcn_mfma_f32_16x16x32_bf16(a00, b, acc0, 0, 0, 0);
    acc1 = __builtin_amdgcn_mfma_f32_16x16x32_bf16(a01, b, acc1, 0, 0, 0);
    acc0 = __builtin_amdgcn_mfma_f32_16x16x32_bf16(a10, b, acc0, 0, 0, 0);
    acc1 = __builtin_amdgcn_mfma_f32_16x16x32_bf16(a11, b, acc1, 0, 0, 0);
    acc0 = __builtin_amdgcn_mfma_f32_16x16x32_bf16(a20, b, acc0, 0, 0, 0);
    acc1 = __builtin_amdgcn_mfma_f32_16x16x32_bf16(a21, b, acc1, 0, 0, 0);
  }
#pragma unroll
  for (int r = 0; r < 4; ++r) {
    yw[wv][kh * 4 + r][lr]      = acc0[r];
    yw[wv][16 + kh * 4 + r][lr] = acc1[r];
  }
  __syncthreads();

  // deterministic 8-way reduce + dinv/2X_i term
  {
    int c = tid >> 4, i = tid & 15;
    float ysum = 0.f;
#pragma unroll
    for (int w = 0; w < 8; ++w) ysum += yw[w][c][i];
    int node = node0 + i;
    float di = dinv[node];
    float xi = X[(size_t)node * 32 + c];
    if (relu_in) xi = fmaxf(xi, 0.f);
    float si = prescaled ? 1.f : di;
    float yt = di * (ysum + 2.f * si * xi);
    if (!HAS_W) {
      yt += bs[c];
      if (relu_out) yt = fmaxf(yt, 0.f);
      out[(size_t)node * 32 + c] = yt;
      if (EMIT_T) {  // next-layer split: split(di * yt)
        unsigned short a, b2, c2; split3(di * yt, a, b2, c2);
        size_t o = (size_t)c * n + node;
        To0[o] = a; To1[o] = b2; To2[o] = c2;
      }
    } else {
      ytot[c][i] = yt;
    }
  }
  if (!HAS_W) return;
  __syncthreads();

  if (HCO == 32) {
    int i = tid >> 5, cf = tid & 31;
    float o = bs[cf];
#pragma unroll
    for (int c = 0; c < 32; ++c) o += ytot[c][i] * Ws[c][cf];
    float ow = relu_out ? fmaxf(o, 0.f) : o;
    out[(size_t)(node0 + i) * 32 + cf] = ow;
    if (EMIT_T) {
      float oT = (EMIT_RELU || relu_out) ? fmaxf(o, 0.f) : o;
      float di = dinv[node0 + i];
      unsigned short a, b2, c2; split3(di * oT, a, b2, c2);
      size_t oidx = (size_t)cf * n + node0 + i;
      To0[oidx] = a; To1[oidx] = b2; To2[oidx] = c2;
    }
  } else {
    int i = tid >> 5, cf = tid & 31;
    if (cf < HCO) {
      float o = bs[cf];
#pragma unroll
      for (int c = 0; c < 32; ++c) o += ytot[c][i] * Ws[c][cf];
      Os[i][cf] = o;
    }
    __syncthreads();
    if (LOGSM) {
      if (tid < 16) {
        int node = node0 + tid;
        float m = Os[tid][0];
#pragma unroll
        for (int c2 = 1; c2 < 7; ++c2) m = fmaxf(m, Os[tid][c2]);
        float ss = 0.f;
#pragma unroll
        for (int c2 = 0; c2 < 7; ++c2) ss += expf(Os[tid][c2] - m);
        float ls = logf(ss);
#pragma unroll
        for (int c2 = 0; c2 < 7; ++c2) out[(size_t)node * 7 + c2] = Os[tid][c2] - m - ls;
      }
    } else {
      if (cf < HCO) out[(size_t)(node0 + i) * 7 + cf] = Os[i][cf];
    }
  }
}

// ---------------- legacy fused GCN layer (f32 A, levels 2-3) -----------------

template <int BF16A, int HCO, int HAS_W, int LOGSM>
__global__ __launch_bounds__(256) void gcn_fused_k(
    const void* __restrict__ Av, const float* __restrict__ X,
    const float* __restrict__ dinv, const float* __restrict__ W,
    const float* __restrict__ bias, float* __restrict__ out,
    int n, int prescaled, int relu_in, int relu_out) {
  __shared__ float As[16][68];
  __shared__ float Xs[64][32];
  __shared__ float Ws[32][32];
  __shared__ float Ys[16][33];
  __shared__ float Os[16][8];
  __shared__ float bs[32];
  int tid = threadIdx.x;
  int rt = tid >> 4, cg = tid & 15;
  int row0 = blockIdx.x * 16;

  if (HAS_W) {
    if (HCO == 32) {
#pragma unroll
      for (int l = 0; l < 4; ++l) {
        int idx = tid + l * 256;
        Ws[idx >> 5][idx & 31] = W[idx];
      }
    } else {
      if (tid < 32 * HCO) Ws[tid / HCO][tid % HCO] = W[tid];
    }
  }
  if (tid < HCO) bs[tid] = bias[tid];

  float acc0 = 0.f, acc1 = 0.f;
  for (int j0 = 0; j0 < n; j0 += 64) {
    __syncthreads();
    {
      int r = tid >> 4, q = (tid & 15) * 4;
      if (BF16A) {
        ushort4 a4 = *(const ushort4*)((const unsigned short*)Av + (size_t)(row0 + r) * n + j0 + q);
        As[r][q + 0] = bf16_to_f32(a4.x);
        As[r][q + 1] = bf16_to_f32(a4.y);
        As[r][q + 2] = bf16_to_f32(a4.z);
        As[r][q + 3] = bf16_to_f32(a4.w);
      } else {
        *(float4*)&As[r][q] = *(const float4*)((const float*)Av + (size_t)(row0 + r) * n + j0 + q);
      }
    }
#pragma unroll
    for (int l = 0; l < 2; ++l) {
      int f = tid + l * 256;
      int r = f >> 3, q = (f & 7) * 4;
      float4 v = *(const float4*)(X + (size_t)(j0 + r) * 32 + q);
      if (relu_in) {
        v.x = fmaxf(v.x, 0.f); v.y = fmaxf(v.y, 0.f);
        v.z = fmaxf(v.z, 0.f); v.w = fmaxf(v.w, 0.f);
      }
      float s = prescaled ? 1.f : dinv[j0 + r];
      Xs[r][q + 0] = s * v.x; Xs[r][q + 1] = s * v.y;
      Xs[r][q + 2] = s * v.z; Xs[r][q + 3] = s * v.w;
    }
    __syncthreads();
#pragma unroll
    for (int j = 0; j < 64; ++j) {
      float av = As[rt][j];
      float2 zv = *(const float2*)&Xs[j][cg * 2];
      acc0 += av * zv.x;
      acc1 += av * zv.y;
    }
  }

  int row = row0 + rt;
  float di = dinv[row];
  int c0 = cg * 2;
  float xa = X[(size_t)row * 32 + c0], xb = X[(size_t)row * 32 + c0 + 1];
  if (relu_in) { xa = fmaxf(xa, 0.f); xb = fmaxf(xb, 0.f); }
  float s_i = prescaled ? 1.f : di;
  float y0 = di * (acc0 + 2.f * s_i * xa);
  float y1 = di * (acc1 + 2.f * s_i * xb);

  if (!HAS_W) {
    y0 += bs[c0]; y1 += bs[c0 + 1];
    if (relu_out) { y0 = fmaxf(y0, 0.f); y1 = fmaxf(y1, 0.f); }
    *(float2*)(out + (size_t)row * 32 + c0) = make_float2(y0, y1);
    return;
  }

  Ys[rt][c0] = y0; Ys[rt][c0 + 1] = y1;
  __syncthreads();
  if (HCO == 32) {
    float o0 = bs[c0], o1 = bs[c0 + 1];
#pragma unroll
    for (int c = 0; c < 32; ++c) {
      float yv = Ys[rt][c];
      o0 += yv * Ws[c][c0];
      o1 += yv * Ws[c][c0 + 1];
    }
    if (relu_out) { o0 = fmaxf(o0, 0.f); o1 = fmaxf(o1, 0.f); }
    *(float2*)(out + (size_t)row * 32 + c0) = make_float2(o0, o1);
  } else {
    if (cg < HCO) {
      float o = bs[cg];
#pragma unroll
      for (int c = 0; c < 32; ++c) o += Ys[rt][c] * Ws[c][cg];
      Os[rt][cg] = o;
    }
    __syncthreads();
    if (LOGSM) {
      if (cg == 0) {
        float m = Os[rt][0];
#pragma unroll
        for (int c = 1; c < 7; ++c) m = fmaxf(m, Os[rt][c]);
        float ss = 0.f;
#pragma unroll
        for (int c = 0; c < 7; ++c) ss += expf(Os[rt][c] - m);
        float ls = logf(ss);
#pragma unroll
        for (int c = 0; c < 7; ++c) out[(size_t)row * 7 + c] = Os[rt][c] - m - ls;
      }
    } else {
      if (cg < HCO) out[(size_t)row * 7 + cg] = Os[rt][cg];
    }
  }
}

// ---------------- top-k machinery ----------------

__global__ void score_k(const float* __restrict__ h, const float* __restrict__ p,
                        float* __restrict__ score, int n) {
  int i = blockIdx.x * 256 + threadIdx.x;
  if (i >= n) return;
  float s = 0.f, pn = 0.f;
#pragma unroll
  for (int c = 0; c < 32; ++c) {
    float pc = p[c];
    s += h[(size_t)i * 32 + c] * pc;
    pn += pc * pc;
  }
  score[i] = tanhf(s / sqrtf(pn));
}

// exact rank by (score desc, index asc); 4 threads per element; writes inv[]
__global__ void topk4_k(const float* __restrict__ score, int* __restrict__ perm,
                        float* __restrict__ vals, int* __restrict__ inv, int n, int k) {
  __shared__ float sc[256];
  int tid = threadIdx.x;
  int e = blockIdx.x * 64 + (tid >> 2);
  int part = tid & 3;
  float si = score[e];
  int rank = 0;
  for (int j0 = 0; j0 < n; j0 += 256) {
    __syncthreads();
    sc[tid] = score[j0 + tid];
    __syncthreads();
    int base = part * 64;
#pragma unroll 16
    for (int jj = 0; jj < 64; ++jj) {
      float sj = sc[base + jj];
      int j = j0 + base + jj;
      rank += (sj > si) || ((sj == si) && (j < e));
    }
  }
  rank += __shfl_xor(rank, 1, 64);
  rank += __shfl_xor(rank, 2, 64);
  if (part == 0) {
    inv[e] = (rank < k) ? rank : -1;
    if (rank < k) { perm[rank] = e; vals[rank] = si; }
  }
}

__global__ void pool_h_k(const float* __restrict__ h, const int* __restrict__ perm,
                         const float* __restrict__ vals, float* __restrict__ out, int k) {
  int idx = blockIdx.x * 256 + threadIdx.x;
  if (idx >= k * 32) return;
  int r = idx >> 5, c = idx & 31;
  out[idx] = h[(size_t)perm[r] * 32 + c] * vals[r];
}

// pool + emit T-split (scale = dinv of pooled level)
__global__ void pool_h_split_k(const float* __restrict__ h, const int* __restrict__ perm,
                               const float* __restrict__ vals, const float* __restrict__ dinv,
                               float* __restrict__ out,
                               unsigned short* __restrict__ T0, unsigned short* __restrict__ T1,
                               unsigned short* __restrict__ T2, int k) {
  int idx = blockIdx.x * 256 + threadIdx.x;
  if (idx >= k * 32) return;
  int r = idx >> 5, c = idx & 31;
  float v = h[(size_t)perm[r] * 32 + c] * vals[r];
  out[idx] = v;
  unsigned short a, b, cc; split3(dinv[r] * v, a, b, cc);
  size_t o = (size_t)c * k + r;
  T0[o] = a; T1[o] = b; T2[o] = cc;
}

// up-path: out[i] = xs[i] + (inv[i]>=0 ? h[inv[i]] : 0)
__global__ void unpool_add_k(const float* __restrict__ xs, const int* __restrict__ inv,
                             const float* __restrict__ h, float* __restrict__ out, int n) {
  int t = blockIdx.x * 256 + threadIdx.x;
  if (t >= n * 8) return;
  int i = t >> 3, c4 = (t & 7) * 4;
  float4 v = *(const float4*)(xs + (size_t)i * 32 + c4);
  int r = inv[i];
  if (r >= 0) {
    float4 u = *(const float4*)(h + (size_t)r * 32 + c4);
    v.x += u.x; v.y += u.y; v.z += u.z; v.w += u.w;
  }
  *(float4*)(out + (size_t)i * 32 + c4) = v;
}

// unpool + emit T-split (scale = dinv)
__global__ void unpool_add_split_k(const float* __restrict__ xs, const int* __restrict__ inv,
                                   const float* __restrict__ h, const float* __restrict__ dinv,
                                   float* __restrict__ out,
                                   unsigned short* __restrict__ T0, unsigned short* __restrict__ T1,
                                   unsigned short* __restrict__ T2, int n) {
  int t = blockIdx.x * 256 + threadIdx.x;
  if (t >= n * 8) return;
  int i = t >> 3, c4 = (t & 7) * 4;
  float4 v = *(const float4*)(xs + (size_t)i * 32 + c4);
  int r = inv[i];
  if (r >= 0) {
    float4 u = *(const float4*)(h + (size_t)r * 32 + c4);
    v.x += u.x; v.y += u.y; v.z += u.z; v.w += u.w;
  }
  *(float4*)(out + (size_t)i * 32 + c4) = v;
  float di = dinv[i];
  float vv[4] = {v.x, v.y, v.z, v.w};
#pragma unroll
  for (int j = 0; j < 4; ++j) {
    unsigned short a, b, cc; split3(di * vv[j], a, b, cc);
    size_t o = (size_t)(c4 + j) * n + i;
    T0[o] = a; T1[o] = b; T2[o] = cc;
  }
}

// ---------------- host orchestration ----------------

extern "C" void kernel_launch(void* const* d_in, const int* in_sizes, int n_in,
                              void* d_out, int out_size, void* d_ws, size_t ws_size,
                              hipStream_t stream) {
  (void)in_sizes; (void)n_in; (void)out_size; (void)ws_size;
  const float* x   = (const float*)d_in[0];
  const int*  eidx = (const int*)d_in[1];
  const float* Wi  = (const float*)d_in[2];
  const float* bi  = (const float*)d_in[3];
  const float* dW  = (const float*)d_in[4];
  const float* db  = (const float*)d_in[5];
  const float* pp  = (const float*)d_in[6];
  const float* uW  = (const float*)d_in[7];
  const float* ub  = (const float*)d_in[8];
  const float* Wf  = (const float*)d_in[9];
  const float* bf  = (const float*)d_in[10];
  float* outp = (float*)d_out;

  char* ws = (char*)d_ws;
  size_t off = 0;
  auto alloc = [&](size_t bytes) -> char* {
    char* p = ws + off;
    off += (bytes + 255) & ~(size_t)255;
    return p;
  };
  const int n0 = 4096, n1 = 2048, n2 = 1024, n3 = 512;
  unsigned short* Abf   = (unsigned short*)alloc((size_t)n0 * n0 * 2);
  unsigned short* As1bf = (unsigned short*)alloc((size_t)n1 * n1 * 2);
  float* As2  = (float*)alloc((size_t)n2 * n2 * 4);
  float* A3   = (float*)alloc((size_t)n3 * n3 * 4);
  unsigned short* Ap  = (unsigned short*)alloc((size_t)n1 * n0 * 2);
  unsigned short* Ap2 = (unsigned short*)alloc((size_t)n2 * n1 * 2);
  float* Ap3 = (float*)alloc((size_t)n3 * n2 * 4);
  // two T-split buffer sets (ping-pong to avoid read/write races)
  unsigned short* TA0 = (unsigned short*)alloc((size_t)n0 * 32 * 2);
  unsigned short* TA1 = (unsigned short*)alloc((size_t)n0 * 32 * 2);
  unsigned short* TA2 = (unsigned short*)alloc((size_t)n0 * 32 * 2);
  unsigned short* TB0 = (unsigned short*)alloc((size_t)n0 * 32 * 2);
  unsigned short* TB1 = (unsigned short*)alloc((size_t)n0 * 32 * 2);
  unsigned short* TB2 = (unsigned short*)alloc((size_t)n0 * 32 * 2);
  float* dinv0 = (float*)alloc(n0 * 4);
  float* dinv1 = (float*)alloc(n1 * 4);
  float* dinv2 = (float*)alloc(n2 * 4);
  float* dinv3 = (float*)alloc(n3 * 4);
  float* Zb    = (float*)alloc((size_t)n0 * 32 * 4);
  float* x0    = (float*)alloc((size_t)n0 * 32 * 4);
  float* xs0   = (float*)alloc((size_t)n0 * 32 * 4);
  float* xs1   = (float*)alloc((size_t)n1 * 32 * 4);
  float* xs2   = (float*)alloc((size_t)n2 * 32 * 4);
  float* hA    = (float*)alloc((size_t)n0 * 32 * 4);
  float* hB    = (float*)alloc((size_t)n0 * 32 * 4);
  float* scb   = (float*)alloc(n0 * 4);
  float* valsb = (float*)alloc(n0 * 4);
  int* perm1 = (int*)alloc(n1 * 4);
  int* perm2 = (int*)alloc(n2 * 4);
  int* perm3 = (int*)alloc(n3 * 4);
  int* inv1  = (int*)alloc(n0 * 4);
  int* inv2  = (int*)alloc(n1 * 4);
  int* inv3  = (int*)alloc(n2 * 4);

  // adjacency (bf16 only)
  hipMemsetAsync(Abf, 0, (size_t)n0 * n0 * 2, stream);
  scatter_edges_k<<<N_EDGE / 256, 256, 0, stream>>>(eidx, eidx + N_EDGE, Abf, n0, N_EDGE);
  deg_dinv_bf16_k<<<n0 / 4, 256, 0, stream>>>(Abf, dinv0, n0);

  // gcn0: Zb = dinv*(x@Wi) (+T emit), x0 = relu(agg) (+T emit for gcn1)
  xw_scale_k<32, 1><<<n0 / 8, dim3(32, 8), 0, stream>>>(x, Wi, dinv0, Zb, TA0, TA1, TA2, n0, F_IN, 0);
  agg_mfma_k<0, 32, 0, 1, 0><<<n0 / 16, 512, 0, stream>>>(
      Abf, TA0, TA1, TA2, Zb, dinv0, nullptr, bi, x0, TB0, TB1, TB2, n0, 1, 0, 1);
  // gcn1 (down_W[0]): xs0 = relu(gcn(x0))
  agg_mfma_k<1, 32, 0, 0, 0><<<n0 / 16, 512, 0, stream>>>(
      Abf, TB0, TB1, TB2, x0, dinv0, dW, db, xs0, nullptr, nullptr, nullptr, n0, 0, 0, 1);

  // ---- level 1 ----
  score_k<<<n0 / 256, 256, 0, stream>>>(xs0, pp, scb, n0);
  topk4_k<<<n0 / 64, 256, 0, stream>>>(scb, perm1, valsb, inv1, n0, n1);
  gather_rows_bf16_k<<<(int)((size_t)n1 * n0 / 8 / 256), 256, 0, stream>>>(Abf, perm1, Ap, n0, 9);
  gemm_bf16_pool_k<<<(n1 / 128) * (n1 / 128), 512, 0, stream>>>(
      (const __hip_bfloat16*)Ap, perm1, nullptr, As1bf, n1, n0);
  deg_dinv_bf16_k<<<n1 / 4, 256, 0, stream>>>(As1bf, dinv1, n1);
  pool_h_split_k<<<n1 * 32 / 256, 256, 0, stream>>>(xs0, perm1, valsb, dinv1, hA, TA0, TA1, TA2, n1);
  agg_mfma_k<1, 32, 0, 0, 0><<<n1 / 16, 512, 0, stream>>>(
      As1bf, TA0, TA1, TA2, hA, dinv1, dW + 1024, db + 32, xs1, nullptr, nullptr, nullptr, n1, 0, 0, 1);

  // ---- level 2 ----
  score_k<<<n1 / 256, 256, 0, stream>>>(xs1, pp + 32, scb, n1);
  topk4_k<<<n1 / 64, 256, 0, stream>>>(scb, perm2, valsb, inv2, n1, n2);
  pool_h_k<<<n2 * 32 / 256, 256, 0, stream>>>(xs1, perm2, valsb, hA, n2);
  gather_rows_bf16_k<<<(int)((size_t)n2 * n1 / 8 / 256), 256, 0, stream>>>(As1bf, perm2, Ap2, n1, 8);
  gemm_bf16_pool_k<<<(n2 / 128) * (n2 / 128), 512, 0, stream>>>(
      (const __hip_bfloat16*)Ap2, perm2, As2, nullptr, n2, n1);
  deg_dinv_f32_k<<<n2 / 4, 256, 0, stream>>>(As2, dinv2, n2);
  gcn_fused_k<0, 32, 1, 0><<<n2 / 16, 256, 0, stream>>>(As2, hA, dinv2, dW + 2048, db + 64, xs2, n2, 0, 0, 1);

  // ---- level 3 (f32 GEMM: values not bf16-exact) ----
  score_k<<<n2 / 256, 256, 0, stream>>>(xs2, pp + 64, scb, n2);
  topk4_k<<<n2 / 64, 256, 0, stream>>>(scb, perm3, valsb, inv3, n2, n3);
  pool_h_k<<<n3 * 32 / 256, 256, 0, stream>>>(xs2, perm3, valsb, hA, n3);
  gather_rows_f32_k<<<(int)((size_t)n3 * n2 / 4 / 256), 256, 0, stream>>>(As2, perm3, Ap3, n2, 8);
  gemm_f32_pool_k<<<(n3 / 32) * (n3 / 32), 256, 0, stream>>>(Ap3, perm3, A3, n3, n2);
  deg_dinv_f32_k<<<n3 / 4, 256, 0, stream>>>(A3, dinv3, n3);
  gcn_fused_k<0, 32, 1, 0><<<n3 / 16, 256, 0, stream>>>(A3, hA, dinv3, dW + 3072, db + 96, hB, n3, 0, 0, 1);

  // ---- up path ----
  unpool_add_k<<<n2 / 32, 256, 0, stream>>>(xs2, inv3, hB, hA, n2);
  gcn_fused_k<0, 32, 1, 0><<<n2 / 16, 256, 0, stream>>>(As2, hA, dinv2, uW, ub, hB, n2, 0, 0, 1);

  unpool_add_split_k<<<n1 / 32, 256, 0, stream>>>(xs1, inv2, hB, dinv1, hA, TA0, TA1, TA2, n1);
  agg_mfma_k<1, 32, 0, 0, 0><<<n1 / 16, 512, 0, stream>>>(
      As1bf, TA0, TA1, TA2, hA, dinv1, uW + 1024, ub + 32, hB, nullptr, nullptr, nullptr, n1, 0, 0, 1);

  unpool_add_split_k<<<n0 / 32, 256, 0, stream>>>(xs0, inv1, hB, dinv0, hA, TA0, TA1, TA2, n0);
  // up agg @4096: out hB (no relu), but emit T with relu+dinv0 for the final layer
  agg_mfma_k<1, 32, 0, 1, 1><<<n0 / 16, 512, 0, stream>>>(
      Abf, TA0, TA1, TA2, hA, dinv0, uW + 2048, ub + 64, hB, TB0, TB1, TB2, n0, 0, 0, 0);

  // final: relu(h) -> gcn(Wf, bf) -> log_softmax, written straight to d_out
  agg_mfma_k<1, 7, 1, 0, 0><<<n0 / 16, 512, 0, stream>>>(
      Abf, TB0, TB1, TB2, hB, dinv0, Wf, bf, outp, nullptr, nullptr, nullptr, n0, 0, 1, 0);
}

// Round 8
// 627.393 us; speedup vs baseline: 1.0429x; 1.0429x over previous
//
#include <hip/hip_runtime.h>
#include <hip/hip_bf16.h>
#include <cstdint>

#define N_NODES 4096
#define F_IN    1433
#define N_EDGE  131072
#define LDW     1536

typedef short short8v __attribute__((ext_vector_type(8)));
typedef float f32x4 __attribute__((ext_vector_type(4)));

#define GLOBAL_AS __attribute__((address_space(1)))
#define LDS_AS    __attribute__((address_space(3)))

__device__ __forceinline__ void gload_lds16(const void* g, void* l) {
  __builtin_amdgcn_global_load_lds((const GLOBAL_AS void*)g, (LDS_AS void*)l, 16, 0, 0);
}

__device__ __forceinline__ float bf16_to_f32(unsigned short u) {
  union { unsigned u; float f; } c;
  c.u = ((unsigned)u) << 16;
  return c.f;
}

__device__ __forceinline__ unsigned short f32_to_bf16_rne(float f) {
  union { float f; unsigned u; } c; c.f = f;
  unsigned u = c.u;
  return (unsigned short)((u + 0x7FFFu + ((u >> 16) & 1u)) >> 16);
}

// exact 3-way bf16 split: a+b+c == v (covers 24 mantissa bits)
__device__ __forceinline__ void split3(float v, unsigned short& a,
                                       unsigned short& b, unsigned short& c) {
  a = f32_to_bf16_rne(v); float r0 = v - bf16_to_f32(a);
  b = f32_to_bf16_rne(r0); float r1 = r0 - bf16_to_f32(b);
  c = f32_to_bf16_rne(r1);
}

// ---------------- adjacency build (bf16 only; exact {0,1}) ----------------

__global__ void scatter_edges_k(const int* __restrict__ e0, const int* __restrict__ e1,
                                unsigned short* __restrict__ Ab, int n, int ne) {
  int t = blockIdx.x * 256 + threadIdx.x;
  if (t >= ne) return;
  int u = e0[t], v = e1[t];
  if (u != v) {
    Ab[(size_t)u * n + v] = 0x3F80;  // bf16 1.0
    Ab[(size_t)v * n + u] = 0x3F80;
  }
}

// deg = rowsum + 2, dinv = 1/sqrt(deg); bf16 input (exact small ints)
__global__ void deg_dinv_bf16_k(const unsigned short* __restrict__ A,
                                float* __restrict__ dinv, int n) {
  int wid  = (blockIdx.x * blockDim.x + threadIdx.x) >> 6;
  int lane = threadIdx.x & 63;
  if (wid >= n) return;
  const unsigned short* row = A + (size_t)wid * n;
  float s = 0.f;
  for (int j = lane * 8; j < n; j += 512) {
    uint4 v = *(const uint4*)(row + j);
    s += bf16_to_f32((unsigned short)(v.x & 0xffff)) + bf16_to_f32((unsigned short)(v.x >> 16));
    s += bf16_to_f32((unsigned short)(v.y & 0xffff)) + bf16_to_f32((unsigned short)(v.y >> 16));
    s += bf16_to_f32((unsigned short)(v.z & 0xffff)) + bf16_to_f32((unsigned short)(v.z >> 16));
    s += bf16_to_f32((unsigned short)(v.w & 0xffff)) + bf16_to_f32((unsigned short)(v.w >> 16));
  }
#pragma unroll
  for (int off = 32; off > 0; off >>= 1) s += __shfl_down(s, off, 64);
  if (lane == 0) {
    float d = s + 2.0f;
    dinv[wid] = d > 0.f ? 1.0f / sqrtf(d) : 0.f;
  }
}

__global__ void deg_dinv_f32_k(const float* __restrict__ A, float* __restrict__ dinv, int n) {
  int wid  = (blockIdx.x * blockDim.x + threadIdx.x) >> 6;
  int lane = threadIdx.x & 63;
  if (wid >= n) return;
  const float* row = A + (size_t)wid * n;
  float s = 0.f;
  for (int j = lane * 4; j < n; j += 256) {
    float4 v = *(const float4*)(row + j);
    s += (v.x + v.y) + (v.z + v.w);
  }
#pragma unroll
  for (int off = 32; off > 0; off >>= 1) s += __shfl_down(s, off, 64);
  if (lane == 0) {
    float d = s + 2.0f;
    dinv[wid] = d > 0.f ? 1.0f / sqrtf(d) : 0.f;
  }
}

// ---------------- row gathers (Ap = M[perm, :]) ----------------

__global__ void gather_rows_bf16_k(const unsigned short* __restrict__ src,
                                   const int* __restrict__ perm,
                                   unsigned short* __restrict__ dst, int K, int cbits) {
  size_t t = (size_t)blockIdx.x * 256 + threadIdx.x;
  int r  = (int)(t >> cbits);
  int c8 = (int)(t & ((1u << cbits) - 1));
  uint4 v = *(const uint4*)(src + (size_t)perm[r] * K + c8 * 8);
  *(uint4*)(dst + t * 8) = v;
}

__global__ void gather_rows_f32_k(const float* __restrict__ src,
                                  const int* __restrict__ perm,
                                  float* __restrict__ dst, int K, int cbits) {
  size_t t = (size_t)blockIdx.x * 256 + threadIdx.x;
  int r  = (int)(t >> cbits);
  int c4 = (int)(t & ((1u << cbits) - 1));
  float4 v = *(const float4*)(src + (size_t)perm[r] * K + c4 * 4);
  *(float4*)(dst + t * 4) = v;
}

// ---------------- pooled augment via bf16 MFMA (8 waves, XCD-chunked) --------
// out[r][s] = dot(Ap[r,:], Ap[s,:]) + 2*Ap[r][perm[s]], diag 0.
// LDS slot-swizzle applied to BOTH gload_lds global source and ds_read slot.

__device__ __forceinline__ void block_map(int bid, int nb, int& bx, int& by) {
  if (nb == 16) {
    int xcd = bid & 7, idx = bid >> 3;
    by = (xcd >> 1) * 4 + (idx >> 3);
    bx = (xcd & 1) * 8 + (idx & 7);
  } else if (nb == 8) {
    int xcd = bid & 7, idx = bid >> 3;
    by = (xcd >> 1) * 2 + (idx >> 2);
    bx = (xcd & 1) * 4 + (idx & 3);
  } else {
    bx = bid % nb; by = bid / nb;
  }
}

__global__ __launch_bounds__(512) void gemm_bf16_pool_k(
    const __hip_bfloat16* __restrict__ Ap, const int* __restrict__ perm,
    float* __restrict__ outF, unsigned short* __restrict__ outB, int M, int K) {
  __shared__ short lds[2][2][128 * 32];
  int nb = M >> 7;
  int bx, by; block_map(blockIdx.x, nb, bx, by);
  int row0 = by << 7, col0 = bx << 7;
  int tid = threadIdx.x;
  int wv = tid >> 6, ln = tid & 63;
  int lr = ln & 15, kh = ln >> 4;
  int wr = wv >> 2, wc = wv & 3;   // 2x4 wave grid; wave tile 64x32

  f32x4 acc[4][2] = {};

  auto stage = [&](int buf, int k0) {
#pragma unroll
    for (int t = 0; t < 2; ++t) {
      int rbase = t ? col0 : row0;
      int row = tid >> 2;
      int gslot = (tid & 3) ^ ((row >> 1) & 3);   // pre-swizzled source slot
      const char* g = (const char*)(Ap + (size_t)(rbase + row) * K + k0) + gslot * 16;
      gload_lds16(g, (char*)&lds[buf][t][0] + wv * 1024);  // wave-uniform base
    }
  };

  int sA = kh ^ ((lr >> 1) & 3);  // read-side swizzled slot
  int nt = K >> 5;
  stage(0, 0);
  int cur = 0;
  for (int kt = 0; kt < nt; ++kt) {
    __syncthreads();
    if (kt + 1 < nt) stage(cur ^ 1, (kt + 1) << 5);
    const short* AbL = &lds[cur][0][0];
    const short* BbL = &lds[cur][1][0];
    short8v af[4], bfr[2];
#pragma unroll
    for (int m = 0; m < 4; ++m)
      af[m] = *(const short8v*)(AbL + (wr * 64 + m * 16 + lr) * 32 + sA * 8);
#pragma unroll
    for (int q = 0; q < 2; ++q)
      bfr[q] = *(const short8v*)(BbL + (wc * 32 + q * 16 + lr) * 32 + sA * 8);
#pragma unroll
    for (int m = 0; m < 4; ++m)
#pragma unroll
      for (int q = 0; q < 2; ++q)
        acc[m][q] = __builtin_amdgcn_mfma_f32_16x16x32_bf16(af[m], bfr[q], acc[m][q], 0, 0, 0);
    cur ^= 1;
  }

#pragma unroll
  for (int q = 0; q < 2; ++q) {
    int col = col0 + wc * 32 + q * 16 + lr;
    int pc  = perm[col];
#pragma unroll
    for (int m = 0; m < 4; ++m) {
      int rb = row0 + wr * 64 + m * 16 + kh * 4;
#pragma unroll
      for (int r = 0; r < 4; ++r) {
        int row = rb + r;
        float v = acc[m][q][r] +
                  2.0f * bf16_to_f32(((const unsigned short*)Ap)[(size_t)row * K + pc]);
        if (row == col) v = 0.f;
        if (outF) outF[(size_t)row * M + col] = v;
        if (outB) {
          union { float f; unsigned u; } c2; c2.f = v;
          outB[(size_t)row * M + col] = (unsigned short)(c2.u >> 16);  // exact small int
        }
      }
    }
  }
}

// ---------------- pooled augment f32 (level 3) ----------------

__global__ __launch_bounds__(256) void gemm_f32_pool_k(
    const float* __restrict__ Ap, const int* __restrict__ perm,
    float* __restrict__ outF, int M, int K) {
  __shared__ float As[32][33];
  __shared__ float Bs[32][33];
  int nb = M >> 5;
  int bx = blockIdx.x % nb, by = blockIdx.x / nb;
  int row0 = by << 5, col0 = bx << 5;
  int tid = threadIdx.x;
  int tr = tid >> 4, tc = tid & 15;
  int lr = tid >> 3, lq = (tid & 7) * 4;
  float acc[2][2] = {};
  for (int k0 = 0; k0 < K; k0 += 32) {
    float4 av = *(const float4*)(Ap + (size_t)(row0 + lr) * K + k0 + lq);
    float4 bv = *(const float4*)(Ap + (size_t)(col0 + lr) * K + k0 + lq);
    __syncthreads();
    As[lq + 0][lr] = av.x; As[lq + 1][lr] = av.y;
    As[lq + 2][lr] = av.z; As[lq + 3][lr] = av.w;
    Bs[lq + 0][lr] = bv.x; Bs[lq + 1][lr] = bv.y;
    Bs[lq + 2][lr] = bv.z; Bs[lq + 3][lr] = bv.w;
    __syncthreads();
#pragma unroll
    for (int k = 0; k < 32; ++k) {
      float2 a = *(const float2*)&As[k][tr * 2];
      float2 b = *(const float2*)&Bs[k][tc * 2];
      acc[0][0] += a.x * b.x; acc[0][1] += a.x * b.y;
      acc[1][0] += a.y * b.x; acc[1][1] += a.y * b.y;
    }
  }
#pragma unroll
  for (int j = 0; j < 2; ++j) {
    int col = col0 + tc * 2 + j;
    int pc = perm[col];
#pragma unroll
    for (int i = 0; i < 2; ++i) {
      int row = row0 + tr * 2 + i;
      float v = acc[i][j] + 2.0f * Ap[(size_t)row * K + pc];
      if (row == col) v = 0.f;
      outF[(size_t)row * M + col] = v;
    }
  }
}

// ---------------- W transpose for layer-0 GEMV: Wt[32][LDW], zero-padded -----

__global__ void wtrans_k(const float* __restrict__ W, float* __restrict__ Wt) {
  int t = blockIdx.x * 256 + threadIdx.x;  // 32*LDW threads
  int c = t / LDW, k = t - c * LDW;
  Wt[t] = (k < F_IN) ? W[(size_t)k * 32 + c] : 0.f;
}

// ---------------- layer-0: Z = dinv_i * (x @ Wi), float4 Wt loads, 4 accs ----

__global__ __launch_bounds__(256) void xw0_k(const float* __restrict__ X,
                                             const float* __restrict__ Wt,
                                             const float* __restrict__ dinv,
                                             float* __restrict__ Z, int n) {
  __shared__ float Xs[8][128];
  int tx = threadIdx.x, ty = threadIdx.y;
  int i0 = blockIdx.x * 8;
  int tid = ty * 32 + tx;
  const float* wrow = Wt + (size_t)tx * LDW;
  float acc0 = 0.f, acc1 = 0.f, acc2 = 0.f, acc3 = 0.f;
  for (int k0 = 0; k0 < F_IN; k0 += 128) {
    __syncthreads();
#pragma unroll
    for (int l = 0; l < 4; ++l) {
      int idx = tid + l * 256;
      int r = idx >> 7, kk = idx & 127;
      Xs[r][kk] = (k0 + kk < F_IN) ? X[(size_t)(i0 + r) * F_IN + k0 + kk] : 0.f;
    }
    __syncthreads();
#pragma unroll 4
    for (int kk = 0; kk < 128; kk += 8) {
      float4 w0 = *(const float4*)(wrow + k0 + kk);
      float4 w1 = *(const float4*)(wrow + k0 + kk + 4);
      float4 x0 = *(const float4*)&Xs[ty][kk];
      float4 x1 = *(const float4*)&Xs[ty][kk + 4];
      acc0 += x0.x * w0.x; acc1 += x0.y * w0.y;
      acc2 += x0.z * w0.z; acc3 += x0.w * w0.w;
      acc0 += x1.x * w1.x; acc1 += x1.y * w1.y;
      acc2 += x1.z * w1.z; acc3 += x1.w * w1.w;
    }
  }
  float z = dinv[i0 + ty] * ((acc0 + acc1) + (acc2 + acc3));
  Z[(size_t)(i0 + ty) * 32 + tx] = z;
}

// ---------------- exact 3-way bf16 split of prescaled X^T (standalone) -------

template <int RELU, int PRESCALED>
__global__ __launch_bounds__(256) void xsplit_k(const float* __restrict__ X,
                                                const float* __restrict__ dinv,
                                                unsigned short* __restrict__ T0,
                                                unsigned short* __restrict__ T1,
                                                unsigned short* __restrict__ T2, int n) {
  __shared__ float Xs[64][33];
  int tid = threadIdx.x;
  int i0 = blockIdx.x * 64;
#pragma unroll
  for (int l = 0; l < 2; ++l) {
    int idx = tid + l * 256;
    int r = idx >> 3, c4 = (idx & 7) * 4;
    float4 v = *(const float4*)(X + (size_t)(i0 + r) * 32 + c4);
    if (RELU) {
      v.x = fmaxf(v.x, 0.f); v.y = fmaxf(v.y, 0.f);
      v.z = fmaxf(v.z, 0.f); v.w = fmaxf(v.w, 0.f);
    }
    float s = PRESCALED ? 1.f : dinv[i0 + r];
    Xs[r][c4 + 0] = s * v.x; Xs[r][c4 + 1] = s * v.y;
    Xs[r][c4 + 2] = s * v.z; Xs[r][c4 + 3] = s * v.w;
  }
  __syncthreads();
  int c = tid >> 3, ib = (tid & 7) * 8;
  unsigned h0[4], h1[4], h2[4];
#pragma unroll
  for (int u = 0; u < 8; u += 2) {
    unsigned short a0, a1, b0, b1, c0, c1;
    split3(Xs[ib + u][c], a0, b0, c0);
    split3(Xs[ib + u + 1][c], a1, b1, c1);
    h0[u >> 1] = (unsigned)a0 | ((unsigned)a1 << 16);
    h1[u >> 1] = (unsigned)b0 | ((unsigned)b1 << 16);
    h2[u >> 1] = (unsigned)c0 | ((unsigned)c1 << 16);
  }
  size_t o = (size_t)c * n + i0 + ib;
  *(uint4*)(T0 + o) = make_uint4(h0[0], h0[1], h0[2], h0[3]);
  *(uint4*)(T1 + o) = make_uint4(h1[0], h1[1], h1[2], h1[3]);
  *(uint4*)(T2 + o) = make_uint4(h2[0], h2[1], h2[2], h2[3]);
}

// ---------------- MFMA GCN aggregation (bf16-exact A) ------------------------

template <int HAS_W, int HCO, int LOGSM, int EMIT_T, int EMIT_RELU>
__global__ __launch_bounds__(512) void agg_mfma_k(
    const unsigned short* __restrict__ Aadj,
    const unsigned short* __restrict__ T0, const unsigned short* __restrict__ T1,
    const unsigned short* __restrict__ T2,
    const float* __restrict__ X, const float* __restrict__ dinv,
    const float* __restrict__ W, const float* __restrict__ bias,
    float* __restrict__ out,
    unsigned short* __restrict__ To0, unsigned short* __restrict__ To1,
    unsigned short* __restrict__ To2,
    int n, int prescaled, int relu_in, int relu_out) {
  __shared__ float yw[8][32][17];
  __shared__ float Ws[32][32];
  __shared__ float ytot[32][17];
  __shared__ float Os[16][8];
  __shared__ float bs[32];
  int tid = threadIdx.x;
  int wv = tid >> 6, ln = tid & 63;
  int lr = ln & 15, kh = ln >> 4;
  int node0 = blockIdx.x * 16;

  if (HAS_W) {
    if (HCO == 32) {
#pragma unroll
      for (int l = 0; l < 2; ++l) {
        int idx = tid + l * 512;
        Ws[idx >> 5][idx & 31] = W[idx];
      }
    } else {
      if (tid < 32 * HCO) Ws[tid / HCO][tid % HCO] = W[tid];
    }
  }
  if (tid < HCO) bs[tid] = bias[tid];

  int kper = n >> 3;
  int kbeg = wv * kper;
  const unsigned short* Ar = Aadj + (size_t)(node0 + lr) * n + kh * 8;
  const unsigned short* t0 = T0 + (size_t)lr * n + kh * 8;
  const unsigned short* t1 = T1 + (size_t)lr * n + kh * 8;
  const unsigned short* t2 = T2 + (size_t)lr * n + kh * 8;
  const size_t m16 = (size_t)16 * n;

  f32x4 acc0 = {0.f, 0.f, 0.f, 0.f}, acc1 = {0.f, 0.f, 0.f, 0.f};
  for (int k = kbeg; k < kbeg + kper; k += 32) {
    short8v b   = *(const short8v*)(Ar + k);
    short8v a00 = *(const short8v*)(t0 + k);
    short8v a01 = *(const short8v*)(t0 + m16 + k);
    short8v a10 = *(const short8v*)(t1 + k);
    short8v a11 = *(const short8v*)(t1 + m16 + k);
    short8v a20 = *(const short8v*)(t2 + k);
    short8v a21 = *(const short8v*)(t2 + m16 + k);
    acc0 = __builtin_amdgcn_mfma_f32_16x16x32_bf16(a00, b, acc0, 0, 0, 0);
    acc1 = __builtin_amdgcn_mfma_f32_16x16x32_bf16(a01, b, acc1, 0, 0, 0);
    acc0 = __builtin_amdgcn_mfma_f32_16x16x32_bf16(a10, b, acc0, 0, 0, 0);
    acc1 = __builtin_amdgcn_mfma_f32_16x16x32_bf16(a11, b, acc1, 0, 0, 0);
    acc0 = __builtin_amdgcn_mfma_f32_16x16x32_bf16(a20, b, acc0, 0, 0, 0);
    acc1 = __builtin_amdgcn_mfma_f32_16x16x32_bf16(a21, b, acc1, 0, 0, 0);
  }
#pragma unroll
  for (int r = 0; r < 4; ++r) {
    yw[wv][kh * 4 + r][lr]      = acc0[r];
    yw[wv][16 + kh * 4 + r][lr] = acc1[r];
  }
  __syncthreads();

  {
    int c = tid >> 4, i = tid & 15;
    float ysum = 0.f;
#pragma unroll
    for (int w = 0; w < 8; ++w) ysum += yw[w][c][i];
    int node = node0 + i;
    float di = dinv[node];
    float xi = X[(size_t)node * 32 + c];
    if (relu_in) xi = fmaxf(xi, 0.f);
    float si = prescaled ? 1.f : di;
    float yt = di * (ysum + 2.f * si * xi);
    if (!HAS_W) {
      yt += bs[c];
      if (relu_out) yt = fmaxf(yt, 0.f);
      out[(size_t)node * 32 + c] = yt;
      if (EMIT_T) {
        unsigned short a, b2, c2; split3(di * yt, a, b2, c2);
        size_t o = (size_t)c * n + node;
        To0[o] = a; To1[o] = b2; To2[o] = c2;
      }
    } else {
      ytot[c][i] = yt;
    }
  }
  if (!HAS_W) return;
  __syncthreads();

  if (HCO == 32) {
    int i = tid >> 5, cf = tid & 31;
    float o = bs[cf];
#pragma unroll
    for (int c = 0; c < 32; ++c) o += ytot[c][i] * Ws[c][cf];
    float ow = relu_out ? fmaxf(o, 0.f) : o;
    out[(size_t)(node0 + i) * 32 + cf] = ow;
    if (EMIT_T) {
      float oT = (EMIT_RELU || relu_out) ? fmaxf(o, 0.f) : o;
      float di = dinv[node0 + i];
      unsigned short a, b2, c2; split3(di * oT, a, b2, c2);
      size_t oidx = (size_t)cf * n + node0 + i;
      To0[oidx] = a; To1[oidx] = b2; To2[oidx] = c2;
    }
  } else {
    int i = tid >> 5, cf = tid & 31;
    if (cf < HCO) {
      float o = bs[cf];
#pragma unroll
      for (int c = 0; c < 32; ++c) o += ytot[c][i] * Ws[c][cf];
      Os[i][cf] = o;
    }
    __syncthreads();
    if (LOGSM) {
      if (tid < 16) {
        int node = node0 + tid;
        float m = Os[tid][0];
#pragma unroll
        for (int c2 = 1; c2 < 7; ++c2) m = fmaxf(m, Os[tid][c2]);
        float ss = 0.f;
#pragma unroll
        for (int c2 = 0; c2 < 7; ++c2) ss += expf(Os[tid][c2] - m);
        float ls = logf(ss);
#pragma unroll
        for (int c2 = 0; c2 < 7; ++c2) out[(size_t)node * 7 + c2] = Os[tid][c2] - m - ls;
      }
    } else {
      if (cf < HCO) out[(size_t)(node0 + i) * 7 + cf] = Os[i][cf];
    }
  }
}

// ---------------- fused GCN layer, f32 A, 8 rows/block (levels 2-3) ----------

__global__ __launch_bounds__(256) void gcn_fused8_k(
    const float* __restrict__ A, const float* __restrict__ X,
    const float* __restrict__ dinv, const float* __restrict__ W,
    const float* __restrict__ bias, float* __restrict__ out, int n, int relu_out) {
  __shared__ float As[8][68];
  __shared__ float Xs[64][32];
  __shared__ float Ws[32][32];
  __shared__ float Ys[8][33];
  __shared__ float bs[32];
  int tid = threadIdx.x;
  int rt = tid >> 5, cg = tid & 31;
  int row0 = blockIdx.x * 8;
#pragma unroll
  for (int l = 0; l < 4; ++l) {
    int idx = tid + l * 256;
    Ws[idx >> 5][idx & 31] = W[idx];
  }
  if (tid < 32) bs[tid] = bias[tid];

  float acc = 0.f;
  for (int j0 = 0; j0 < n; j0 += 64) {
    __syncthreads();
    if (tid < 128) {
      int r = tid >> 4, q = (tid & 15) * 4;
      *(float4*)&As[r][q] = *(const float4*)(A + (size_t)(row0 + r) * n + j0 + q);
    }
#pragma unroll
    for (int l = 0; l < 2; ++l) {
      int f = tid + l * 256;
      int r = f >> 3, q = (f & 7) * 4;
      float4 v = *(const float4*)(X + (size_t)(j0 + r) * 32 + q);
      float s = dinv[j0 + r];
      Xs[r][q + 0] = s * v.x; Xs[r][q + 1] = s * v.y;
      Xs[r][q + 2] = s * v.z; Xs[r][q + 3] = s * v.w;
    }
    __syncthreads();
#pragma unroll
    for (int j = 0; j < 64; ++j) acc += As[rt][j] * Xs[j][cg];
  }
  int row = row0 + rt;
  float di = dinv[row];
  float xi = X[(size_t)row * 32 + cg];
  float y = di * (acc + 2.f * di * xi);
  Ys[rt][cg] = y;
  __syncthreads();
  float o = bs[cg];
#pragma unroll
  for (int c = 0; c < 32; ++c) o += Ys[rt][c] * Ws[c][cg];
  if (relu_out) o = fmaxf(o, 0.f);
  out[(size_t)row * 32 + cg] = o;
}

// ---------------- top-k machinery ----------------

__global__ void score_k(const float* __restrict__ h, const float* __restrict__ p,
                        float* __restrict__ score, int n) {
  int i = blockIdx.x * 256 + threadIdx.x;
  if (i >= n) return;
  float s = 0.f, pn = 0.f;
#pragma unroll
  for (int c = 0; c < 32; ++c) {
    float pc = p[c];
    s += h[(size_t)i * 32 + c] * pc;
    pn += pc * pc;
  }
  score[i] = tanhf(s / sqrtf(pn));
}

// exact rank by (score desc, index asc); 4 threads per element; writes inv[]
__global__ void topk4_k(const float* __restrict__ score, int* __restrict__ perm,
                        float* __restrict__ vals, int* __restrict__ inv, int n, int k) {
  __shared__ float sc[256];
  int tid = threadIdx.x;
  int e = blockIdx.x * 64 + (tid >> 2);
  int part = tid & 3;
  float si = score[e];
  int rank = 0;
  for (int j0 = 0; j0 < n; j0 += 256) {
    __syncthreads();
    sc[tid] = score[j0 + tid];
    __syncthreads();
    int base = part * 64;
#pragma unroll 16
    for (int jj = 0; jj < 64; ++jj) {
      float sj = sc[base + jj];
      int j = j0 + base + jj;
      rank += (sj > si) || ((sj == si) && (j < e));
    }
  }
  rank += __shfl_xor(rank, 1, 64);
  rank += __shfl_xor(rank, 2, 64);
  if (part == 0) {
    inv[e] = (rank < k) ? rank : -1;
    if (rank < k) { perm[rank] = e; vals[rank] = si; }
  }
}

__global__ void pool_h_k(const float* __restrict__ h, const int* __restrict__ perm,
                         const float* __restrict__ vals, float* __restrict__ out, int k) {
  int idx = blockIdx.x * 256 + threadIdx.x;
  if (idx >= k * 32) return;
  int r = idx >> 5, c = idx & 31;
  out[idx] = h[(size_t)perm[r] * 32 + c] * vals[r];
}

// pool + emit T-split (scale = dinv of pooled level)
__global__ void pool_h_split_k(const float* __restrict__ h, const int* __restrict__ perm,
                               const float* __restrict__ vals, const float* __restrict__ dinv,
                               float* __restrict__ out,
                               unsigned short* __restrict__ T0, unsigned short* __restrict__ T1,
                               unsigned short* __restrict__ T2, int k) {
  int idx = blockIdx.x * 256 + threadIdx.x;
  if (idx >= k * 32) return;
  int r = idx >> 5, c = idx & 31;
  float v = h[(size_t)perm[r] * 32 + c] * vals[r];
  out[idx] = v;
  unsigned short a, b, cc; split3(dinv[r] * v, a, b, cc);
  size_t o = (size_t)c * k + r;
  T0[o] = a; T1[o] = b; T2[o] = cc;
}

// up-path: out[i] = xs[i] + (inv[i]>=0 ? h[inv[i]] : 0)
__global__ void unpool_add_k(const float* __restrict__ xs, const int* __restrict__ inv,
                             const float* __restrict__ h, float* __restrict__ out, int n) {
  int t = blockIdx.x * 256 + threadIdx.x;
  if (t >= n * 8) return;
  int i = t >> 3, c4 = (t & 7) * 4;
  float4 v = *(const float4*)(xs + (size_t)i * 32 + c4);
  int r = inv[i];
  if (r >= 0) {
    float4 u = *(const float4*)(h + (size_t)r * 32 + c4);
    v.x += u.x; v.y += u.y; v.z += u.z; v.w += u.w;
  }
  *(float4*)(out + (size_t)i * 32 + c4) = v;
}

// unpool + emit T-split (scale = dinv)
__global__ void unpool_add_split_k(const float* __restrict__ xs, const int* __restrict__ inv,
                                   const float* __restrict__ h, const float* __restrict__ dinv,
                                   float* __restrict__ out,
                                   unsigned short* __restrict__ T0, unsigned short* __restrict__ T1,
                                   unsigned short* __restrict__ T2, int n) {
  int t = blockIdx.x * 256 + threadIdx.x;
  if (t >= n * 8) return;
  int i = t >> 3, c4 = (t & 7) * 4;
  float4 v = *(const float4*)(xs + (size_t)i * 32 + c4);
  int r = inv[i];
  if (r >= 0) {
    float4 u = *(const float4*)(h + (size_t)r * 32 + c4);
    v.x += u.x; v.y += u.y; v.z += u.z; v.w += u.w;
  }
  *(float4*)(out + (size_t)i * 32 + c4) = v;
  float di = dinv[i];
  float vv[4] = {v.x, v.y, v.z, v.w};
#pragma unroll
  for (int j = 0; j < 4; ++j) {
    unsigned short a, b, cc; split3(di * vv[j], a, b, cc);
    size_t o = (size_t)(c4 + j) * n + i;
    T0[o] = a; T1[o] = b; T2[o] = cc;
  }
}

// ---------------- host orchestration ----------------

extern "C" void kernel_launch(void* const* d_in, const int* in_sizes, int n_in,
                              void* d_out, int out_size, void* d_ws, size_t ws_size,
                              hipStream_t stream) {
  (void)in_sizes; (void)n_in; (void)out_size; (void)ws_size;
  const float* x   = (const float*)d_in[0];
  const int*  eidx = (const int*)d_in[1];
  const float* Wi  = (const float*)d_in[2];
  const float* bi  = (const float*)d_in[3];
  const float* dW  = (const float*)d_in[4];
  const float* db  = (const float*)d_in[5];
  const float* pp  = (const float*)d_in[6];
  const float* uW  = (const float*)d_in[7];
  const float* ub  = (const float*)d_in[8];
  const float* Wf  = (const float*)d_in[9];
  const float* bf  = (const float*)d_in[10];
  float* outp = (float*)d_out;

  char* ws = (char*)d_ws;
  size_t off = 0;
  auto alloc = [&](size_t bytes) -> char* {
    char* p = ws + off;
    off += (bytes + 255) & ~(size_t)255;
    return p;
  };
  const int n0 = 4096, n1 = 2048, n2 = 1024, n3 = 512;
  unsigned short* Abf   = (unsigned short*)alloc((size_t)n0 * n0 * 2);
  unsigned short* As1bf = (unsigned short*)alloc((size_t)n1 * n1 * 2);
  float* As2  = (float*)alloc((size_t)n2 * n2 * 4);
  float* A3   = (float*)alloc((size_t)n3 * n3 * 4);
  unsigned short* Ap  = (unsigned short*)alloc((size_t)n1 * n0 * 2);
  unsigned short* Ap2 = (unsigned short*)alloc((size_t)n2 * n1 * 2);
  float* Ap3 = (float*)alloc((size_t)n3 * n2 * 4);
  unsigned short* TA0 = (unsigned short*)alloc((size_t)n0 * 32 * 2);
  unsigned short* TA1 = (unsigned short*)alloc((size_t)n0 * 32 * 2);
  unsigned short* TA2 = (unsigned short*)alloc((size_t)n0 * 32 * 2);
  unsigned short* TB0 = (unsigned short*)alloc((size_t)n0 * 32 * 2);
  unsigned short* TB1 = (unsigned short*)alloc((size_t)n0 * 32 * 2);
  unsigned short* TB2 = (unsigned short*)alloc((size_t)n0 * 32 * 2);
  float* Wt   = (float*)alloc((size_t)32 * LDW * 4);
  float* dinv0 = (float*)alloc(n0 * 4);
  float* dinv1 = (float*)alloc(n1 * 4);
  float* dinv2 = (float*)alloc(n2 * 4);
  float* dinv3 = (float*)alloc(n3 * 4);
  float* Zb    = (float*)alloc((size_t)n0 * 32 * 4);
  float* x0    = (float*)alloc((size_t)n0 * 32 * 4);
  float* xs0   = (float*)alloc((size_t)n0 * 32 * 4);
  float* xs1   = (float*)alloc((size_t)n1 * 32 * 4);
  float* xs2   = (float*)alloc((size_t)n2 * 32 * 4);
  float* hA    = (float*)alloc((size_t)n0 * 32 * 4);
  float* hB    = (float*)alloc((size_t)n0 * 32 * 4);
  float* scb   = (float*)alloc(n0 * 4);
  float* valsb = (float*)alloc(n0 * 4);
  int* perm1 = (int*)alloc(n1 * 4);
  int* perm2 = (int*)alloc(n2 * 4);
  int* perm3 = (int*)alloc(n3 * 4);
  int* inv1  = (int*)alloc(n0 * 4);
  int* inv2  = (int*)alloc(n1 * 4);
  int* inv3  = (int*)alloc(n2 * 4);

  // adjacency (bf16 only) + W transpose
  hipMemsetAsync(Abf, 0, (size_t)n0 * n0 * 2, stream);
  scatter_edges_k<<<N_EDGE / 256, 256, 0, stream>>>(eidx, eidx + N_EDGE, Abf, n0, N_EDGE);
  wtrans_k<<<32 * LDW / 256, 256, 0, stream>>>(Wi, Wt);
  deg_dinv_bf16_k<<<n0 / 4, 256, 0, stream>>>(Abf, dinv0, n0);

  // gcn0: Zb = dinv*(x@Wi); split; x0 = relu(agg) (+T emit for gcn1)
  xw0_k<<<n0 / 8, dim3(32, 8), 0, stream>>>(x, Wt, dinv0, Zb, n0);
  xsplit_k<0, 1><<<n0 / 64, 256, 0, stream>>>(Zb, dinv0, TA0, TA1, TA2, n0);
  agg_mfma_k<0, 32, 0, 1, 0><<<n0 / 16, 512, 0, stream>>>(
      Abf, TA0, TA1, TA2, Zb, dinv0, nullptr, bi, x0, TB0, TB1, TB2, n0, 1, 0, 1);
  // gcn1 (down_W[0]): xs0 = relu(gcn(x0))
  agg_mfma_k<1, 32, 0, 0, 0><<<n0 / 16, 512, 0, stream>>>(
      Abf, TB0, TB1, TB2, x0, dinv0, dW, db, xs0, nullptr, nullptr, nullptr, n0, 0, 0, 1);

  // ---- level 1 ----
  score_k<<<n0 / 256, 256, 0, stream>>>(xs0, pp, scb, n0);
  topk4_k<<<n0 / 64, 256, 0, stream>>>(scb, perm1, valsb, inv1, n0, n1);
  gather_rows_bf16_k<<<(int)((size_t)n1 * n0 / 8 / 256), 256, 0, stream>>>(Abf, perm1, Ap, n0, 9);
  gemm_bf16_pool_k<<<(n1 / 128) * (n1 / 128), 512, 0, stream>>>(
      (const __hip_bfloat16*)Ap, perm1, nullptr, As1bf, n1, n0);
  deg_dinv_bf16_k<<<n1 / 4, 256, 0, stream>>>(As1bf, dinv1, n1);
  pool_h_split_k<<<n1 * 32 / 256, 256, 0, stream>>>(xs0, perm1, valsb, dinv1, hA, TA0, TA1, TA2, n1);
  agg_mfma_k<1, 32, 0, 0, 0><<<n1 / 16, 512, 0, stream>>>(
      As1bf, TA0, TA1, TA2, hA, dinv1, dW + 1024, db + 32, xs1, nullptr, nullptr, nullptr, n1, 0, 0, 1);

  // ---- level 2 ----
  score_k<<<n1 / 256, 256, 0, stream>>>(xs1, pp + 32, scb, n1);
  topk4_k<<<n1 / 64, 256, 0, stream>>>(scb, perm2, valsb, inv2, n1, n2);
  pool_h_k<<<n2 * 32 / 256, 256, 0, stream>>>(xs1, perm2, valsb, hA, n2);
  gather_rows_bf16_k<<<(int)((size_t)n2 * n1 / 8 / 256), 256, 0, stream>>>(As1bf, perm2, Ap2, n1, 8);
  gemm_bf16_pool_k<<<(n2 / 128) * (n2 / 128), 512, 0, stream>>>(
      (const __hip_bfloat16*)Ap2, perm2, As2, nullptr, n2, n1);
  deg_dinv_f32_k<<<n2 / 4, 256, 0, stream>>>(As2, dinv2, n2);
  gcn_fused8_k<<<n2 / 8, 256, 0, stream>>>(As2, hA, dinv2, dW + 2048, db + 64, xs2, n2, 1);

  // ---- level 3 (f32 GEMM: values not bf16-exact) ----
  score_k<<<n2 / 256, 256, 0, stream>>>(xs2, pp + 64, scb, n2);
  topk4_k<<<n2 / 64, 256, 0, stream>>>(scb, perm3, valsb, inv3, n2, n3);
  pool_h_k<<<n3 * 32 / 256, 256, 0, stream>>>(xs2, perm3, valsb, hA, n3);
  gather_rows_f32_k<<<(int)((size_t)n3 * n2 / 4 / 256), 256, 0, stream>>>(As2, perm3, Ap3, n2, 8);
  gemm_f32_pool_k<<<(n3 / 32) * (n3 / 32), 256, 0, stream>>>(Ap3, perm3, A3, n3, n2);
  deg_dinv_f32_k<<<n3 / 4, 256, 0, stream>>>(A3, dinv3, n3);
  gcn_fused8_k<<<n3 / 8, 256, 0, stream>>>(A3, hA, dinv3, dW + 3072, db + 96, hB, n3, 1);

  // ---- up path ----
  unpool_add_k<<<n2 / 32, 256, 0, stream>>>(xs2, inv3, hB, hA, n2);
  gcn_fused8_k<<<n2 / 8, 256, 0, stream>>>(As2, hA, dinv2, uW, ub, hB, n2, 1);

  unpool_add_split_k<<<n1 / 32, 256, 0, stream>>>(xs1, inv2, hB, dinv1, hA, TA0, TA1, TA2, n1);
  agg_mfma_k<1, 32, 0, 0, 0><<<n1 / 16, 512, 0, stream>>>(
      As1bf, TA0, TA1, TA2, hA, dinv1, uW + 1024, ub + 32, hB, nullptr, nullptr, nullptr, n1, 0, 0, 1);

  unpool_add_split_k<<<n0 / 32, 256, 0, stream>>>(xs0, inv1, hB, dinv0, hA, TA0, TA1, TA2, n0);
  // up agg @4096: out hB (no relu), emit T with relu+dinv0 for the final layer
  agg_mfma_k<1, 32, 0, 1, 1><<<n0 / 16, 512, 0, stream>>>(
      Abf, TA0, TA1, TA2, hA, dinv0, uW + 2048, ub + 64, hB, TB0, TB1, TB2, n0, 0, 0, 0);

  // final: relu(h) -> gcn(Wf, bf) -> log_softmax, written straight to d_out
  agg_mfma_k<1, 7, 1, 0, 0><<<n0 / 16, 512, 0, stream>>>(
      Abf, TB0, TB1, TB2, hB, dinv0, Wf, bf, outp, nullptr, nullptr, nullptr, n0, 0, 1, 0);
}

// Round 11
// 625.865 us; speedup vs baseline: 1.0455x; 1.0024x over previous
//
#include <hip/hip_runtime.h>
#include <hip/hip_bf16.h>
#include <cstdint>

#define N_NODES 4096
#define F_IN    1433
#define N_EDGE  131072
#define LDW     1536
#define KCHUNK  6

typedef short short8v __attribute__((ext_vector_type(8)));
typedef float f32x4 __attribute__((ext_vector_type(4)));

#define GLOBAL_AS __attribute__((address_space(1)))
#define LDS_AS    __attribute__((address_space(3)))

__device__ __forceinline__ void gload_lds16(const void* g, void* l) {
  __builtin_amdgcn_global_load_lds((const GLOBAL_AS void*)g, (LDS_AS void*)l, 16, 0, 0);
}

__device__ __forceinline__ float bf16_to_f32(unsigned short u) {
  union { unsigned u; float f; } c;
  c.u = ((unsigned)u) << 16;
  return c.f;
}

__device__ __forceinline__ unsigned short f32_to_bf16_rne(float f) {
  union { float f; unsigned u; } c; c.f = f;
  unsigned u = c.u;
  return (unsigned short)((u + 0x7FFFu + ((u >> 16) & 1u)) >> 16);
}

// exact 3-way bf16 split: a+b+c == v (covers 24 mantissa bits)
__device__ __forceinline__ void split3(float v, unsigned short& a,
                                       unsigned short& b, unsigned short& c) {
  a = f32_to_bf16_rne(v); float r0 = v - bf16_to_f32(a);
  b = f32_to_bf16_rne(r0); float r1 = r0 - bf16_to_f32(b);
  c = f32_to_bf16_rne(r1);
}

// ---------------- adjacency build (bf16 only; exact {0,1}) ----------------

__global__ void scatter_edges_k(const int* __restrict__ e0, const int* __restrict__ e1,
                                unsigned short* __restrict__ Ab, int n, int ne) {
  int t = blockIdx.x * 256 + threadIdx.x;
  if (t >= ne) return;
  int u = e0[t], v = e1[t];
  if (u != v) {
    Ab[(size_t)u * n + v] = 0x3F80;  // bf16 1.0
    Ab[(size_t)v * n + u] = 0x3F80;
  }
}

// deg = rowsum + 2, dinv = 1/sqrt(deg); bf16 input (exact small ints)
__global__ void deg_dinv_bf16_k(const unsigned short* __restrict__ A,
                                float* __restrict__ dinv, int n) {
  int wid  = (blockIdx.x * blockDim.x + threadIdx.x) >> 6;
  int lane = threadIdx.x & 63;
  if (wid >= n) return;
  const unsigned short* row = A + (size_t)wid * n;
  float s = 0.f;
  for (int j = lane * 8; j < n; j += 512) {
    uint4 v = *(const uint4*)(row + j);
    s += bf16_to_f32((unsigned short)(v.x & 0xffff)) + bf16_to_f32((unsigned short)(v.x >> 16));
    s += bf16_to_f32((unsigned short)(v.y & 0xffff)) + bf16_to_f32((unsigned short)(v.y >> 16));
    s += bf16_to_f32((unsigned short)(v.z & 0xffff)) + bf16_to_f32((unsigned short)(v.z >> 16));
    s += bf16_to_f32((unsigned short)(v.w & 0xffff)) + bf16_to_f32((unsigned short)(v.w >> 16));
  }
#pragma unroll
  for (int off = 32; off > 0; off >>= 1) s += __shfl_down(s, off, 64);
  if (lane == 0) {
    float d = s + 2.0f;
    dinv[wid] = d > 0.f ? 1.0f / sqrtf(d) : 0.f;
  }
}

__global__ void deg_dinv_f32_k(const float* __restrict__ A, float* __restrict__ dinv, int n) {
  int wid  = (blockIdx.x * blockDim.x + threadIdx.x) >> 6;
  int lane = threadIdx.x & 63;
  if (wid >= n) return;
  const float* row = A + (size_t)wid * n;
  float s = 0.f;
  for (int j = lane * 4; j < n; j += 256) {
    float4 v = *(const float4*)(row + j);
    s += (v.x + v.y) + (v.z + v.w);
  }
#pragma unroll
  for (int off = 32; off > 0; off >>= 1) s += __shfl_down(s, off, 64);
  if (lane == 0) {
    float d = s + 2.0f;
    dinv[wid] = d > 0.f ? 1.0f / sqrtf(d) : 0.f;
  }
}

// ---------------- row gathers (Ap = M[perm, :]) ----------------

__global__ void gather_rows_bf16_k(const unsigned short* __restrict__ src,
                                   const int* __restrict__ perm,
                                   unsigned short* __restrict__ dst, int K, int cbits) {
  size_t t = (size_t)blockIdx.x * 256 + threadIdx.x;
  int r  = (int)(t >> cbits);
  int c8 = (int)(t & ((1u << cbits) - 1));
  uint4 v = *(const uint4*)(src + (size_t)perm[r] * K + c8 * 8);
  *(uint4*)(dst + t * 8) = v;
}

__global__ void gather_rows_f32_k(const float* __restrict__ src,
                                  const int* __restrict__ perm,
                                  float* __restrict__ dst, int K, int cbits) {
  size_t t = (size_t)blockIdx.x * 256 + threadIdx.x;
  int r  = (int)(t >> cbits);
  int c4 = (int)(t & ((1u << cbits) - 1));
  float4 v = *(const float4*)(src + (size_t)perm[r] * K + c4 * 4);
  *(float4*)(dst + t * 4) = v;
}

// ---------------- pooled augment via bf16 MFMA (8 waves, XCD-chunked) --------
// out[r][s] = dot(Ap[r,:], Ap[s,:]) + 2*Ap[r][perm[s]], diag 0.
// LDS slot-swizzle applied to BOTH gload_lds global source and ds_read slot.

__device__ __forceinline__ void block_map(int bid, int nb, int& bx, int& by) {
  if (nb == 16) {
    int xcd = bid & 7, idx = bid >> 3;
    by = (xcd >> 1) * 4 + (idx >> 3);
    bx = (xcd & 1) * 8 + (idx & 7);
  } else if (nb == 8) {
    int xcd = bid & 7, idx = bid >> 3;
    by = (xcd >> 1) * 2 + (idx >> 2);
    bx = (xcd & 1) * 4 + (idx & 3);
  } else {
    bx = bid % nb; by = bid / nb;
  }
}

__global__ __launch_bounds__(512) void gemm_bf16_pool_k(
    const __hip_bfloat16* __restrict__ Ap, const int* __restrict__ perm,
    float* __restrict__ outF, unsigned short* __restrict__ outB, int M, int K) {
  __shared__ short lds[2][2][128 * 32];
  int nb = M >> 7;
  int bx, by; block_map(blockIdx.x, nb, bx, by);
  int row0 = by << 7, col0 = bx << 7;
  int tid = threadIdx.x;
  int wv = tid >> 6, ln = tid & 63;
  int lr = ln & 15, kh = ln >> 4;
  int wr = wv >> 2, wc = wv & 3;   // 2x4 wave grid; wave tile 64x32

  f32x4 acc[4][2] = {};

  auto stage = [&](int buf, int k0) {
#pragma unroll
    for (int t = 0; t < 2; ++t) {
      int rbase = t ? col0 : row0;
      int row = tid >> 2;
      int gslot = (tid & 3) ^ ((row >> 1) & 3);   // pre-swizzled source slot
      const char* g = (const char*)(Ap + (size_t)(rbase + row) * K + k0) + gslot * 16;
      gload_lds16(g, (char*)&lds[buf][t][0] + wv * 1024);  // wave-uniform base
    }
  };

  int sA = kh ^ ((lr >> 1) & 3);  // read-side swizzled slot
  int nt = K >> 5;
  stage(0, 0);
  int cur = 0;
  for (int kt = 0; kt < nt; ++kt) {
    __syncthreads();
    if (kt + 1 < nt) stage(cur ^ 1, (kt + 1) << 5);
    const short* AbL = &lds[cur][0][0];
    const short* BbL = &lds[cur][1][0];
    short8v af[4], bfr[2];
#pragma unroll
    for (int m = 0; m < 4; ++m)
      af[m] = *(const short8v*)(AbL + (wr * 64 + m * 16 + lr) * 32 + sA * 8);
#pragma unroll
    for (int q = 0; q < 2; ++q)
      bfr[q] = *(const short8v*)(BbL + (wc * 32 + q * 16 + lr) * 32 + sA * 8);
#pragma unroll
    for (int m = 0; m < 4; ++m)
#pragma unroll
      for (int q = 0; q < 2; ++q)
        acc[m][q] = __builtin_amdgcn_mfma_f32_16x16x32_bf16(af[m], bfr[q], acc[m][q], 0, 0, 0);
    cur ^= 1;
  }

#pragma unroll
  for (int q = 0; q < 2; ++q) {
    int col = col0 + wc * 32 + q * 16 + lr;
    int pc  = perm[col];
#pragma unroll
    for (int m = 0; m < 4; ++m) {
      int rb = row0 + wr * 64 + m * 16 + kh * 4;
#pragma unroll
      for (int r = 0; r < 4; ++r) {
        int row = rb + r;
        float v = acc[m][q][r] +
                  2.0f * bf16_to_f32(((const unsigned short*)Ap)[(size_t)row * K + pc]);
        if (row == col) v = 0.f;
        if (outF) outF[(size_t)row * M + col] = v;
        if (outB) {
          union { float f; unsigned u; } c2; c2.f = v;
          outB[(size_t)row * M + col] = (unsigned short)(c2.u >> 16);  // exact small int
        }
      }
    }
  }
}

// ---------------- pooled augment f32 (level 3) ----------------

__global__ __launch_bounds__(256) void gemm_f32_pool_k(
    const float* __restrict__ Ap, const int* __restrict__ perm,
    float* __restrict__ outF, int M, int K) {
  __shared__ float As[32][33];
  __shared__ float Bs[32][33];
  int nb = M >> 5;
  int bx = blockIdx.x % nb, by = blockIdx.x / nb;
  int row0 = by << 5, col0 = bx << 5;
  int tid = threadIdx.x;
  int tr = tid >> 4, tc = tid & 15;
  int lr = tid >> 3, lq = (tid & 7) * 4;
  float acc[2][2] = {};
  for (int k0 = 0; k0 < K; k0 += 32) {
    float4 av = *(const float4*)(Ap + (size_t)(row0 + lr) * K + k0 + lq);
    float4 bv = *(const float4*)(Ap + (size_t)(col0 + lr) * K + k0 + lq);
    __syncthreads();
    As[lq + 0][lr] = av.x; As[lq + 1][lr] = av.y;
    As[lq + 2][lr] = av.z; As[lq + 3][lr] = av.w;
    Bs[lq + 0][lr] = bv.x; Bs[lq + 1][lr] = bv.y;
    Bs[lq + 2][lr] = bv.z; Bs[lq + 3][lr] = bv.w;
    __syncthreads();
#pragma unroll
    for (int k = 0; k < 32; ++k) {
      float2 a = *(const float2*)&As[k][tr * 2];
      float2 b = *(const float2*)&Bs[k][tc * 2];
      acc[0][0] += a.x * b.x; acc[0][1] += a.x * b.y;
      acc[1][0] += a.y * b.x; acc[1][1] += a.y * b.y;
    }
  }
#pragma unroll
  for (int j = 0; j < 2; ++j) {
    int col = col0 + tc * 2 + j;
    int pc = perm[col];
#pragma unroll
    for (int i = 0; i < 2; ++i) {
      int row = row0 + tr * 2 + i;
      float v = acc[i][j] + 2.0f * Ap[(size_t)row * K + pc];
      if (row == col) v = 0.f;
      outF[(size_t)row * M + col] = v;
    }
  }
}

// ---------------- W transpose for layer-0 GEMV: Wt[32][LDW], zero-padded -----

__global__ void wtrans_k(const float* __restrict__ W, float* __restrict__ Wt) {
  int t = blockIdx.x * 256 + threadIdx.x;  // 32*LDW threads
  int c = t / LDW, k = t - c * LDW;
  Wt[t] = (k < F_IN) ? W[(size_t)k * 32 + c] : 0.f;
}

// ---------------- layer-0 GEMV, k-split: partial sums over 6 chunks ----------
// grid = KCHUNK * (n/8); part[ch][row][col]

__global__ __launch_bounds__(256) void xw0_part_k(const float* __restrict__ X,
                                                  const float* __restrict__ Wt,
                                                  float* __restrict__ part, int n) {
  __shared__ float Xs[8][128];
  int tx = threadIdx.x, ty = threadIdx.y;
  int rowblk = blockIdx.x & 511;   // n/8 = 512 row-blocks
  int ch = blockIdx.x >> 9;        // 0..5
  int i0 = rowblk * 8;
  int tid = ty * 32 + tx;
  int kbeg = ch * 256;
  const float* wrow = Wt + (size_t)tx * LDW;
  float acc0 = 0.f, acc1 = 0.f, acc2 = 0.f, acc3 = 0.f;
  for (int k0 = kbeg; k0 < kbeg + 256; k0 += 128) {
    __syncthreads();
#pragma unroll
    for (int l = 0; l < 4; ++l) {
      int idx = tid + l * 256;
      int r = idx >> 7, kk = idx & 127;
      Xs[r][kk] = (k0 + kk < F_IN) ? X[(size_t)(i0 + r) * F_IN + k0 + kk] : 0.f;
    }
    __syncthreads();
#pragma unroll 4
    for (int kk = 0; kk < 128; kk += 8) {
      float4 w0 = *(const float4*)(wrow + k0 + kk);
      float4 w1 = *(const float4*)(wrow + k0 + kk + 4);
      float4 x0 = *(const float4*)&Xs[ty][kk];
      float4 x1 = *(const float4*)&Xs[ty][kk + 4];
      acc0 += x0.x * w0.x; acc1 += x0.y * w0.y;
      acc2 += x0.z * w0.z; acc3 += x0.w * w0.w;
      acc0 += x1.x * w1.x; acc1 += x1.y * w1.y;
      acc2 += x1.z * w1.z; acc3 += x1.w * w1.w;
    }
  }
  part[(size_t)ch * n * 32 + (size_t)(i0 + ty) * 32 + tx] = (acc0 + acc1) + (acc2 + acc3);
}

// reduce 6 partials, apply dinv: Z = dinv * sum_ch part[ch]
__global__ void xw0_reduce_k(const float* __restrict__ part, const float* __restrict__ dinv,
                             float* __restrict__ Z, int n) {
  int t = blockIdx.x * 256 + threadIdx.x;  // n*8 threads
  int r = t >> 3, c4 = (t & 7) * 4;
  float4 s = {0.f, 0.f, 0.f, 0.f};
#pragma unroll
  for (int ch = 0; ch < KCHUNK; ++ch) {
    float4 v = *(const float4*)(part + (size_t)ch * n * 32 + (size_t)r * 32 + c4);
    s.x += v.x; s.y += v.y; s.z += v.z; s.w += v.w;
  }
  float di = dinv[r];
  s.x *= di; s.y *= di; s.z *= di; s.w *= di;
  *(float4*)(Z + (size_t)r * 32 + c4) = s;
}

// ---------------- exact 3-way bf16 split of prescaled X^T (standalone) -------

template <int RELU, int PRESCALED>
__global__ __launch_bounds__(256) void xsplit_k(const float* __restrict__ X,
                                                const float* __restrict__ dinv,
                                                unsigned short* __restrict__ T0,
                                                unsigned short* __restrict__ T1,
                                                unsigned short* __restrict__ T2, int n) {
  __shared__ float Xs[64][33];
  int tid = threadIdx.x;
  int i0 = blockIdx.x * 64;
#pragma unroll
  for (int l = 0; l < 2; ++l) {
    int idx = tid + l * 256;
    int r = idx >> 3, c4 = (idx & 7) * 4;
    float4 v = *(const float4*)(X + (size_t)(i0 + r) * 32 + c4);
    if (RELU) {
      v.x = fmaxf(v.x, 0.f); v.y = fmaxf(v.y, 0.f);
      v.z = fmaxf(v.z, 0.f); v.w = fmaxf(v.w, 0.f);
    }
    float s = PRESCALED ? 1.f : dinv[i0 + r];
    Xs[r][c4 + 0] = s * v.x; Xs[r][c4 + 1] = s * v.y;
    Xs[r][c4 + 2] = s * v.z; Xs[r][c4 + 3] = s * v.w;
  }
  __syncthreads();
  int c = tid >> 3, ib = (tid & 7) * 8;
  unsigned h0[4], h1[4], h2[4];
#pragma unroll
  for (int u = 0; u < 8; u += 2) {
    unsigned short a0, a1, b0, b1, c0, c1;
    split3(Xs[ib + u][c], a0, b0, c0);
    split3(Xs[ib + u + 1][c], a1, b1, c1);
    h0[u >> 1] = (unsigned)a0 | ((unsigned)a1 << 16);
    h1[u >> 1] = (unsigned)b0 | ((unsigned)b1 << 16);
    h2[u >> 1] = (unsigned)c0 | ((unsigned)c1 << 16);
  }
  size_t o = (size_t)c * n + i0 + ib;
  *(uint4*)(T0 + o) = make_uint4(h0[0], h0[1], h0[2], h0[3]);
  *(uint4*)(T1 + o) = make_uint4(h1[0], h1[1], h1[2], h1[3]);
  *(uint4*)(T2 + o) = make_uint4(h2[0], h2[1], h2[2], h2[3]);
}

// ---------------- MFMA GCN aggregation (bf16-exact A) ------------------------

template <int HAS_W, int HCO, int LOGSM, int EMIT_T, int EMIT_RELU>
__global__ __launch_bounds__(512) void agg_mfma_k(
    const unsigned short* __restrict__ Aadj,
    const unsigned short* __restrict__ T0, const unsigned short* __restrict__ T1,
    const unsigned short* __restrict__ T2,
    const float* __restrict__ X, const float* __restrict__ dinv,
    const float* __restrict__ W, const float* __restrict__ bias,
    float* __restrict__ out,
    unsigned short* __restrict__ To0, unsigned short* __restrict__ To1,
    unsigned short* __restrict__ To2,
    int n, int prescaled, int relu_in, int relu_out) {
  __shared__ float yw[8][32][17];
  __shared__ float Ws[32][32];
  __shared__ float ytot[32][17];
  __shared__ float Os[16][8];
  __shared__ float bs[32];
  int tid = threadIdx.x;
  int wv = tid >> 6, ln = tid & 63;
  int lr = ln & 15, kh = ln >> 4;
  int node0 = blockIdx.x * 16;

  if (HAS_W) {
    if (HCO == 32) {
#pragma unroll
      for (int l = 0; l < 2; ++l) {
        int idx = tid + l * 512;
        Ws[idx >> 5][idx & 31] = W[idx];
      }
    } else {
      if (tid < 32 * HCO) Ws[tid / HCO][tid % HCO] = W[tid];
    }
  }
  if (tid < HCO) bs[tid] = bias[tid];

  int kper = n >> 3;
  int kbeg = wv * kper;
  const unsigned short* Ar = Aadj + (size_t)(node0 + lr) * n + kh * 8;
  const unsigned short* t0 = T0 + (size_t)lr * n + kh * 8;
  const unsigned short* t1 = T1 + (size_t)lr * n + kh * 8;
  const unsigned short* t2 = T2 + (size_t)lr * n + kh * 8;
  const size_t m16 = (size_t)16 * n;

  f32x4 acc0 = {0.f, 0.f, 0.f, 0.f}, acc1 = {0.f, 0.f, 0.f, 0.f};
  for (int k = kbeg; k < kbeg + kper; k += 32) {
    short8v b   = *(const short8v*)(Ar + k);
    short8v a00 = *(const short8v*)(t0 + k);
    short8v a01 = *(const short8v*)(t0 + m16 + k);
    short8v a10 = *(const short8v*)(t1 + k);
    short8v a11 = *(const short8v*)(t1 + m16 + k);
    short8v a20 = *(const short8v*)(t2 + k);
    short8v a21 = *(const short8v*)(t2 + m16 + k);
    acc0 = __builtin_amdgcn_mfma_f32_16x16x32_bf16(a00, b, acc0, 0, 0, 0);
    acc1 = __builtin_amdgcn_mfma_f32_16x16x32_bf16(a01, b, acc1, 0, 0, 0);
    acc0 = __builtin_amdgcn_mfma_f32_16x16x32_bf16(a10, b, acc0, 0, 0, 0);
    acc1 = __builtin_amdgcn_mfma_f32_16x16x32_bf16(a11, b, acc1, 0, 0, 0);
    acc0 = __builtin_amdgcn_mfma_f32_16x16x32_bf16(a20, b, acc0, 0, 0, 0);
    acc1 = __builtin_amdgcn_mfma_f32_16x16x32_bf16(a21, b, acc1, 0, 0, 0);
  }
#pragma unroll
  for (int r = 0; r < 4; ++r) {
    yw[wv][kh * 4 + r][lr]      = acc0[r];
    yw[wv][16 + kh * 4 + r][lr] = acc1[r];
  }
  __syncthreads();

  {
    int c = tid >> 4, i = tid & 15;
    float ysum = 0.f;
#pragma unroll
    for (int w = 0; w < 8; ++w) ysum += yw[w][c][i];
    int node = node0 + i;
    float di = dinv[node];
    float xi = X[(size_t)node * 32 + c];
    if (relu_in) xi = fmaxf(xi, 0.f);
    float si = prescaled ? 1.f : di;
    float yt = di * (ysum + 2.f * si * xi);
    if (!HAS_W) {
      yt += bs[c];
      if (relu_out) yt = fmaxf(yt, 0.f);
      out[(size_t)node * 32 + c] = yt;
      if (EMIT_T) {
        unsigned short a, b2, c2; split3(di * yt, a, b2, c2);
        size_t o = (size_t)c * n + node;
        To0[o] = a; To1[o] = b2; To2[o] = c2;
      }
    } else {
      ytot[c][i] = yt;
    }
  }
  if (!HAS_W) return;
  __syncthreads();

  if (HCO == 32) {
    int i = tid >> 5, cf = tid & 31;
    float o = bs[cf];
#pragma unroll
    for (int c = 0; c < 32; ++c) o += ytot[c][i] * Ws[c][cf];
    float ow = relu_out ? fmaxf(o, 0.f) : o;
    out[(size_t)(node0 + i) * 32 + cf] = ow;
    if (EMIT_T) {
      float oT = (EMIT_RELU || relu_out) ? fmaxf(o, 0.f) : o;
      float di = dinv[node0 + i];
      unsigned short a, b2, c2; split3(di * oT, a, b2, c2);
      size_t oidx = (size_t)cf * n + node0 + i;
      To0[oidx] = a; To1[oidx] = b2; To2[oidx] = c2;
    }
  } else {
    int i = tid >> 5, cf = tid & 31;
    if (cf < HCO) {
      float o = bs[cf];
#pragma unroll
      for (int c = 0; c < 32; ++c) o += ytot[c][i] * Ws[c][cf];
      Os[i][cf] = o;
    }
    __syncthreads();
    if (LOGSM) {
      if (tid < 16) {
        int node = node0 + tid;
        float m = Os[tid][0];
#pragma unroll
        for (int c2 = 1; c2 < 7; ++c2) m = fmaxf(m, Os[tid][c2]);
        float ss = 0.f;
#pragma unroll
        for (int c2 = 0; c2 < 7; ++c2) ss += expf(Os[tid][c2] - m);
        float ls = logf(ss);
#pragma unroll
        for (int c2 = 0; c2 < 7; ++c2) out[(size_t)node * 7 + c2] = Os[tid][c2] - m - ls;
      }
    } else {
      if (cf < HCO) out[(size_t)(node0 + i) * 7 + cf] = Os[i][cf];
    }
  }
}

// ---------------- fused GCN layer, f32 A, 8 rows/block (levels 2-3) ----------

__global__ __launch_bounds__(256) void gcn_fused8_k(
    const float* __restrict__ A, const float* __restrict__ X,
    const float* __restrict__ dinv, const float* __restrict__ W,
    const float* __restrict__ bias, float* __restrict__ out, int n, int relu_out) {
  __shared__ float As[8][68];
  __shared__ float Xs[64][32];
  __shared__ float Ws[32][32];
  __shared__ float Ys[8][33];
  __shared__ float bs[32];
  int tid = threadIdx.x;
  int rt = tid >> 5, cg = tid & 31;
  int row0 = blockIdx.x * 8;
#pragma unroll
  for (int l = 0; l < 4; ++l) {
    int idx = tid + l * 256;
    Ws[idx >> 5][idx & 31] = W[idx];
  }
  if (tid < 32) bs[tid] = bias[tid];

  float acc = 0.f;
  for (int j0 = 0; j0 < n; j0 += 64) {
    __syncthreads();
    if (tid < 128) {
      int r = tid >> 4, q = (tid & 15) * 4;
      *(float4*)&As[r][q] = *(const float4*)(A + (size_t)(row0 + r) * n + j0 + q);
    }
#pragma unroll
    for (int l = 0; l < 2; ++l) {
      int f = tid + l * 256;
      int r = f >> 3, q = (f & 7) * 4;
      float4 v = *(const float4*)(X + (size_t)(j0 + r) * 32 + q);
      float s = dinv[j0 + r];
      Xs[r][q + 0] = s * v.x; Xs[r][q + 1] = s * v.y;
      Xs[r][q + 2] = s * v.z; Xs[r][q + 3] = s * v.w;
    }
    __syncthreads();
#pragma unroll
    for (int j = 0; j < 64; ++j) acc += As[rt][j] * Xs[j][cg];
  }
  int row = row0 + rt;
  float di = dinv[row];
  float xi = X[(size_t)row * 32 + cg];
  float y = di * (acc + 2.f * di * xi);
  Ys[rt][cg] = y;
  __syncthreads();
  float o = bs[cg];
#pragma unroll
  for (int c = 0; c < 32; ++c) o += Ys[rt][c] * Ws[c][cg];
  if (relu_out) o = fmaxf(o, 0.f);
  out[(size_t)row * 32 + cg] = o;
}

// ---------------- top-k machinery ----------------

__global__ void score_k(const float* __restrict__ h, const float* __restrict__ p,
                        float* __restrict__ score, int n) {
  int i = blockIdx.x * 256 + threadIdx.x;
  if (i >= n) return;
  float s = 0.f, pn = 0.f;
#pragma unroll
  for (int c = 0; c < 32; ++c) {
    float pc = p[c];
    s += h[(size_t)i * 32 + c] * pc;
    pn += pc * pc;
  }
  score[i] = tanhf(s / sqrtf(pn));
}

// exact rank by (score desc, index asc); 4 threads per element; writes inv[]
__global__ void topk4_k(const float* __restrict__ score, int* __restrict__ perm,
                        float* __restrict__ vals, int* __restrict__ inv, int n, int k) {
  __shared__ float sc[256];
  int tid = threadIdx.x;
  int e = blockIdx.x * 64 + (tid >> 2);
  int part = tid & 3;
  float si = score[e];
  int rank = 0;
  for (int j0 = 0; j0 < n; j0 += 256) {
    __syncthreads();
    sc[tid] = score[j0 + tid];
    __syncthreads();
    int base = part * 64;
#pragma unroll 16
    for (int jj = 0; jj < 64; ++jj) {
      float sj = sc[base + jj];
      int j = j0 + base + jj;
      rank += (sj > si) || ((sj == si) && (j < e));
    }
  }
  rank += __shfl_xor(rank, 1, 64);
  rank += __shfl_xor(rank, 2, 64);
  if (part == 0) {
    inv[e] = (rank < k) ? rank : -1;
    if (rank < k) { perm[rank] = e; vals[rank] = si; }
  }
}

__global__ void pool_h_k(const float* __restrict__ h, const int* __restrict__ perm,
                         const float* __restrict__ vals, float* __restrict__ out, int k) {
  int idx = blockIdx.x * 256 + threadIdx.x;
  if (idx >= k * 32) return;
  int r = idx >> 5, c = idx & 31;
  out[idx] = h[(size_t)perm[r] * 32 + c] * vals[r];
}

// pool + emit T-split (scale = dinv of pooled level)
__global__ void pool_h_split_k(const float* __restrict__ h, const int* __restrict__ perm,
                               const float* __restrict__ vals, const float* __restrict__ dinv,
                               float* __restrict__ out,
                               unsigned short* __restrict__ T0, unsigned short* __restrict__ T1,
                               unsigned short* __restrict__ T2, int k) {
  int idx = blockIdx.x * 256 + threadIdx.x;
  if (idx >= k * 32) return;
  int r = idx >> 5, c = idx & 31;
  float v = h[(size_t)perm[r] * 32 + c] * vals[r];
  out[idx] = v;
  unsigned short a, b, cc; split3(dinv[r] * v, a, b, cc);
  size_t o = (size_t)c * k + r;
  T0[o] = a; T1[o] = b; T2[o] = cc;
}

// up-path: out[i] = xs[i] + (inv[i]>=0 ? h[inv[i]] : 0)
__global__ void unpool_add_k(const float* __restrict__ xs, const int* __restrict__ inv,
                             const float* __restrict__ h, float* __restrict__ out, int n) {
  int t = blockIdx.x * 256 + threadIdx.x;
  if (t >= n * 8) return;
  int i = t >> 3, c4 = (t & 7) * 4;
  float4 v = *(const float4*)(xs + (size_t)i * 32 + c4);
  int r = inv[i];
  if (r >= 0) {
    float4 u = *(const float4*)(h + (size_t)r * 32 + c4);
    v.x += u.x; v.y += u.y; v.z += u.z; v.w += u.w;
  }
  *(float4*)(out + (size_t)i * 32 + c4) = v;
}

// unpool + emit T-split (scale = dinv)
__global__ void unpool_add_split_k(const float* __restrict__ xs, const int* __restrict__ inv,
                                   const float* __restrict__ h, const float* __restrict__ dinv,
                                   float* __restrict__ out,
                                   unsigned short* __restrict__ T0, unsigned short* __restrict__ T1,
                                   unsigned short* __restrict__ T2, int n) {
  int t = blockIdx.x * 256 + threadIdx.x;
  if (t >= n * 8) return;
  int i = t >> 3, c4 = (t & 7) * 4;
  float4 v = *(const float4*)(xs + (size_t)i * 32 + c4);
  int r = inv[i];
  if (r >= 0) {
    float4 u = *(const float4*)(h + (size_t)r * 32 + c4);
    v.x += u.x; v.y += u.y; v.z += u.z; v.w += u.w;
  }
  *(float4*)(out + (size_t)i * 32 + c4) = v;
  float di = dinv[i];
  float vv[4] = {v.x, v.y, v.z, v.w};
#pragma unroll
  for (int j = 0; j < 4; ++j) {
    unsigned short a, b, cc; split3(di * vv[j], a, b, cc);
    size_t o = (size_t)(c4 + j) * n + i;
    T0[o] = a; T1[o] = b; T2[o] = cc;
  }
}

// ---------------- host orchestration ----------------

extern "C" void kernel_launch(void* const* d_in, const int* in_sizes, int n_in,
                              void* d_out, int out_size, void* d_ws, size_t ws_size,
                              hipStream_t stream) {
  (void)in_sizes; (void)n_in; (void)out_size; (void)ws_size;
  const float* x   = (const float*)d_in[0];
  const int*  eidx = (const int*)d_in[1];
  const float* Wi  = (const float*)d_in[2];
  const float* bi  = (const float*)d_in[3];
  const float* dW  = (const float*)d_in[4];
  const float* db  = (const float*)d_in[5];
  const float* pp  = (const float*)d_in[6];
  const float* uW  = (const float*)d_in[7];
  const float* ub  = (const float*)d_in[8];
  const float* Wf  = (const float*)d_in[9];
  const float* bf  = (const float*)d_in[10];
  float* outp = (float*)d_out;

  char* ws = (char*)d_ws;
  size_t off = 0;
  auto alloc = [&](size_t bytes) -> char* {
    char* p = ws + off;
    off += (bytes + 255) & ~(size_t)255;
    return p;
  };
  const int n0 = 4096, n1 = 2048, n2 = 1024, n3 = 512;
  unsigned short* Abf   = (unsigned short*)alloc((size_t)n0 * n0 * 2);
  unsigned short* As1bf = (unsigned short*)alloc((size_t)n1 * n1 * 2);
  float* As2  = (float*)alloc((size_t)n2 * n2 * 4);
  float* A3   = (float*)alloc((size_t)n3 * n3 * 4);
  unsigned short* Ap  = (unsigned short*)alloc((size_t)n1 * n0 * 2);
  unsigned short* Ap2 = (unsigned short*)alloc((size_t)n2 * n1 * 2);
  float* Ap3 = (float*)alloc((size_t)n3 * n2 * 4);
  unsigned short* TA0 = (unsigned short*)alloc((size_t)n0 * 32 * 2);
  unsigned short* TA1 = (unsigned short*)alloc((size_t)n0 * 32 * 2);
  unsigned short* TA2 = (unsigned short*)alloc((size_t)n0 * 32 * 2);
  unsigned short* TB0 = (unsigned short*)alloc((size_t)n0 * 32 * 2);
  unsigned short* TB1 = (unsigned short*)alloc((size_t)n0 * 32 * 2);
  unsigned short* TB2 = (unsigned short*)alloc((size_t)n0 * 32 * 2);
  float* Wt   = (float*)alloc((size_t)32 * LDW * 4);
  float* part = (float*)alloc((size_t)KCHUNK * n0 * 32 * 4);
  float* dinv0 = (float*)alloc(n0 * 4);
  float* dinv1 = (float*)alloc(n1 * 4);
  float* dinv2 = (float*)alloc(n2 * 4);
  float* dinv3 = (float*)alloc(n3 * 4);
  float* Zb    = (float*)alloc((size_t)n0 * 32 * 4);
  float* x0    = (float*)alloc((size_t)n0 * 32 * 4);
  float* xs0   = (float*)alloc((size_t)n0 * 32 * 4);
  float* xs1   = (float*)alloc((size_t)n1 * 32 * 4);
  float* xs2   = (float*)alloc((size_t)n2 * 32 * 4);
  float* hA    = (float*)alloc((size_t)n0 * 32 * 4);
  float* hB    = (float*)alloc((size_t)n0 * 32 * 4);
  float* scb   = (float*)alloc(n0 * 4);
  float* valsb = (float*)alloc(n0 * 4);
  int* perm1 = (int*)alloc(n1 * 4);
  int* perm2 = (int*)alloc(n2 * 4);
  int* perm3 = (int*)alloc(n3 * 4);
  int* inv1  = (int*)alloc(n0 * 4);
  int* inv2  = (int*)alloc(n1 * 4);
  int* inv3  = (int*)alloc(n2 * 4);

  // adjacency (bf16 only) + W transpose
  hipMemsetAsync(Abf, 0, (size_t)n0 * n0 * 2, stream);
  scatter_edges_k<<<N_EDGE / 256, 256, 0, stream>>>(eidx, eidx + N_EDGE, Abf, n0, N_EDGE);
  wtrans_k<<<32 * LDW / 256, 256, 0, stream>>>(Wi, Wt);
  deg_dinv_bf16_k<<<n0 / 4, 256, 0, stream>>>(Abf, dinv0, n0);

  // gcn0: Zb = dinv*(x@Wi) via k-split partials; split; x0 = relu(agg)
  xw0_part_k<<<KCHUNK * (n0 / 8), dim3(32, 8), 0, stream>>>(x, Wt, part, n0);
  xw0_reduce_k<<<n0 * 8 / 256, 256, 0, stream>>>(part, dinv0, Zb, n0);
  xsplit_k<0, 1><<<n0 / 64, 256, 0, stream>>>(Zb, dinv0, TA0, TA1, TA2, n0);
  agg_mfma_k<0, 32, 0, 1, 0><<<n0 / 16, 512, 0, stream>>>(
      Abf, TA0, TA1, TA2, Zb, dinv0, nullptr, bi, x0, TB0, TB1, TB2, n0, 1, 0, 1);
  // gcn1 (down_W[0]): xs0 = relu(gcn(x0))
  agg_mfma_k<1, 32, 0, 0, 0><<<n0 / 16, 512, 0, stream>>>(
      Abf, TB0, TB1, TB2, x0, dinv0, dW, db, xs0, nullptr, nullptr, nullptr, n0, 0, 0, 1);

  // ---- level 1 ----
  score_k<<<n0 / 256, 256, 0, stream>>>(xs0, pp, scb, n0);
  topk4_k<<<n0 / 64, 256, 0, stream>>>(scb, perm1, valsb, inv1, n0, n1);
  gather_rows_bf16_k<<<(int)((size_t)n1 * n0 / 8 / 256), 256, 0, stream>>>(Abf, perm1, Ap, n0, 9);
  gemm_bf16_pool_k<<<(n1 / 128) * (n1 / 128), 512, 0, stream>>>(
      (const __hip_bfloat16*)Ap, perm1, nullptr, As1bf, n1, n0);
  deg_dinv_bf16_k<<<n1 / 4, 256, 0, stream>>>(As1bf, dinv1, n1);
  pool_h_split_k<<<n1 * 32 / 256, 256, 0, stream>>>(xs0, perm1, valsb, dinv1, hA, TA0, TA1, TA2, n1);
  agg_mfma_k<1, 32, 0, 0, 0><<<n1 / 16, 512, 0, stream>>>(
      As1bf, TA0, TA1, TA2, hA, dinv1, dW + 1024, db + 32, xs1, nullptr, nullptr, nullptr, n1, 0, 0, 1);

  // ---- level 2 ----
  score_k<<<n1 / 256, 256, 0, stream>>>(xs1, pp + 32, scb, n1);
  topk4_k<<<n1 / 64, 256, 0, stream>>>(scb, perm2, valsb, inv2, n1, n2);
  pool_h_k<<<n2 * 32 / 256, 256, 0, stream>>>(xs1, perm2, valsb, hA, n2);
  gather_rows_bf16_k<<<(int)((size_t)n2 * n1 / 8 / 256), 256, 0, stream>>>(As1bf, perm2, Ap2, n1, 8);
  gemm_bf16_pool_k<<<(n2 / 128) * (n2 / 128), 512, 0, stream>>>(
      (const __hip_bfloat16*)Ap2, perm2, As2, nullptr, n2, n1);
  deg_dinv_f32_k<<<n2 / 4, 256, 0, stream>>>(As2, dinv2, n2);
  gcn_fused8_k<<<n2 / 8, 256, 0, stream>>>(As2, hA, dinv2, dW + 2048, db + 64, xs2, n2, 1);

  // ---- level 3 (f32 GEMM: values not bf16-exact) ----
  score_k<<<n2 / 256, 256, 0, stream>>>(xs2, pp + 64, scb, n2);
  topk4_k<<<n2 / 64, 256, 0, stream>>>(scb, perm3, valsb, inv3, n2, n3);
  pool_h_k<<<n3 * 32 / 256, 256, 0, stream>>>(xs2, perm3, valsb, hA, n3);
  gather_rows_f32_k<<<(int)((size_t)n3 * n2 / 4 / 256), 256, 0, stream>>>(As2, perm3, Ap3, n2, 8);
  gemm_f32_pool_k<<<(n3 / 32) * (n3 / 32), 256, 0, stream>>>(Ap3, perm3, A3, n3, n2);
  deg_dinv_f32_k<<<n3 / 4, 256, 0, stream>>>(A3, dinv3, n3);
  gcn_fused8_k<<<n3 / 8, 256, 0, stream>>>(A3, hA, dinv3, dW + 3072, db + 96, hB, n3, 1);

  // ---- up path ----
  unpool_add_k<<<n2 / 32, 256, 0, stream>>>(xs2, inv3, hB, hA, n2);
  gcn_fused8_k<<<n2 / 8, 256, 0, stream>>>(As2, hA, dinv2, uW, ub, hB, n2, 1);

  unpool_add_split_k<<<n1 / 32, 256, 0, stream>>>(xs1, inv2, hB, dinv1, hA, TA0, TA1, TA2, n1);
  agg_mfma_k<1, 32, 0, 0, 0><<<n1 / 16, 512, 0, stream>>>(
      As1bf, TA0, TA1, TA2, hA, dinv1, uW + 1024, ub + 32, hB, nullptr, nullptr, nullptr, n1, 0, 0, 1);

  unpool_add_split_k<<<n0 / 32, 256, 0, stream>>>(xs0, inv1, hB, dinv0, hA, TA0, TA1, TA2, n0);
  // up agg @4096: out hB (no relu), emit T with relu+dinv0 for the final layer
  agg_mfma_k<1, 32, 0, 1, 1><<<n0 / 16, 512, 0, stream>>>(
      Abf, TA0, TA1, TA2, hA, dinv0, uW + 2048, ub + 64, hB, TB0, TB1, TB2, n0, 0, 0, 0);

  // final: relu(h) -> gcn(Wf, bf) -> log_softmax, written straight to d_out
  agg_mfma_k<1, 7, 1, 0, 0><<<n0 / 16, 512, 0, stream>>>(
      Abf, TB0, TB1, TB2, hB, dinv0, Wf, bf, outp, nullptr, nullptr, nullptr, n0, 0, 1, 0);
}